// Round 4
// baseline (415.991 us; speedup 1.0000x reference)
//
#include <hip/hip_runtime.h>
#include <hip/hip_bf16.h>
#include <hip/hip_cooperative_groups.h>

namespace cg = cooperative_groups;

typedef __bf16 bf16x8 __attribute__((ext_vector_type(8)));
typedef float f32x4 __attribute__((ext_vector_type(4)));

#define B_ 4
#define L_ 2048
#define D_ 512
#define H_ 8
#define QS 2048
#define SP 72

#define SB0 __builtin_amdgcn_sched_barrier(0)
#define WAIT_VM(n) asm volatile("s_waitcnt vmcnt(" #n ")" ::: "memory")
#define WAIT_LGKM0 asm volatile("s_waitcnt lgkmcnt(0)" ::: "memory")

// async 16B global -> LDS (gfx950 global_load_lds_dwordx4)
__device__ __forceinline__ void gl16(const __bf16* g, __bf16* l) {
  __builtin_amdgcn_global_load_lds(
      (const __attribute__((address_space(1))) void*)g,
      (__attribute__((address_space(3))) void*)l, 16, 0, 0);
}

// ===========================================================================
// MEGA cooperative kernel: cvt -> QKVU gemm -> attn -> out gemm, one dispatch.
// grid 256 x 512thr x 128KB dyn LDS = 1 block/CU (cooperative-valid).
// Removes 3 kernel-launch boundaries; stages separated by grid.sync().
// ===========================================================================
__global__ __launch_bounds__(512, 2) void mega(
    const float* __restrict__ x,  const float* __restrict__ wq,
    const float* __restrict__ wu, const float* __restrict__ wo,
    const float* __restrict__ bq, const float* __restrict__ bu,
    const float* __restrict__ bo,
    __bf16* __restrict__ xb, __bf16* __restrict__ wcat,
    __bf16* __restrict__ wob, float* __restrict__ bcat,
    __bf16* __restrict__ qu, __bf16* __restrict__ gb,
    float* __restrict__ out)
{
  extern __shared__ char smem[];
  cg::grid_group gg = cg::this_grid();
  const int t = threadIdx.x;
  const int blk = blockIdx.x;
  const int lane = t & 63;
  const int wave = t >> 6;

  // ================= stage 0: f32->bf16 cvt/pack (grid-stride) =============
  {
#pragma unroll
    for (int it = 0; it < 6; ++it) {
      const int idx8 = blk * 512 + t + it * 131072;
      if (idx8 < 688128) {
        const float* src; __bf16* dst; size_t so, dof;
        if (idx8 < 524288)      { src = x;  dst = xb;   so = (size_t)idx8 * 8;            dof = so; }
        else if (idx8 < 622592) { src = wq; dst = wcat; so = (size_t)(idx8 - 524288) * 8; dof = so; }
        else if (idx8 < 655360) { src = wu; dst = wcat; so = (size_t)(idx8 - 622592) * 8; dof = so + 786432; }
        else                    { src = wo; dst = wob;  so = (size_t)(idx8 - 655360) * 8; dof = so; }
        const float4 lo = *(const float4*)(src + so);
        const float4 hi = *(const float4*)(src + so + 4);
        bf16x8 r;
        r[0] = (__bf16)lo.x; r[1] = (__bf16)lo.y; r[2] = (__bf16)lo.z; r[3] = (__bf16)lo.w;
        r[4] = (__bf16)hi.x; r[5] = (__bf16)hi.y; r[6] = (__bf16)hi.z; r[7] = (__bf16)hi.w;
        *(bf16x8*)(dst + dof) = r;
      }
    }
    if (blk == 0 && t < 256) {
#pragma unroll
      for (int e = 0; e < 8; ++e) {
        const int col = t * 8 + e;
        bcat[col] = (col < 1536) ? bq[col] : bu[col - 1536];
      }
    }
  }
  __threadfence();
  gg.sync();

  // ================= stage 1: QKVU gemm, 256x256 pipelined ================
  // qu[8192][2048] = xb[8192][512] @ wcat[2048][512]^T + bcat
  {
    const int bm0 = (blk & 31) * 256;
    const int bn0 = (blk >> 5) * 256;
    const int wm = (wave >> 2) * 128;
    const int wn = (wave & 3) * 64;
    const int r = lane & 15, q = lane >> 4;

    auto stage = [&](int kt, int p) {
#pragma unroll
      for (int j = 0; j < 4; ++j) {
        const int c = t + j * 512;
        const int row = c >> 3;
        const int cs = (c & 7) ^ (row & 7);
        gl16(xb + (size_t)(bm0 + row) * 512 + kt * 64 + cs * 8,
             (__bf16*)(smem + p * 32768) + c * 8);
      }
#pragma unroll
      for (int j = 0; j < 4; ++j) {
        const int c = t + j * 512;
        const int row = c >> 3;
        const int cs = (c & 7) ^ (row & 7);
        gl16(wcat + (size_t)(bn0 + row) * 512 + kt * 64 + cs * 8,
             (__bf16*)(smem + 65536 + p * 32768) + c * 8);
      }
    };
    auto rdA = [&](int p, int mi, int ks) -> bf16x8 {
      const int row = wm + mi * 16 + r;
      const int byte = row * 128 + ((ks * 64 + q * 16) ^ ((row & 7) << 4));
      return *(const bf16x8*)(smem + p * 32768 + byte);
    };
    auto rdB = [&](int p, int ni, int ks) -> bf16x8 {
      const int row = wn + ni * 16 + r;
      const int byte = row * 128 + ((ks * 64 + q * 16) ^ ((row & 7) << 4));
      return *(const bf16x8*)(smem + 65536 + p * 32768 + byte);
    };

    f32x4 acc[8][4] = {};
    WAIT_VM(0);                 // deterministic vmcnt baseline
    stage(0, 0);
    stage(1, 1);

    for (int kt = 0; kt < 8; ++kt) {
      const int p = kt & 1;
      if (kt < 7) { WAIT_VM(8); } else { WAIT_VM(0); }
      SB0; __builtin_amdgcn_s_barrier(); SB0;

      bf16x8 a03[4][2], a47[4][2], b01[2][2], b23[2][2];
      // ph0
#pragma unroll
      for (int mi = 0; mi < 4; ++mi) { a03[mi][0] = rdA(p, mi, 0); a03[mi][1] = rdA(p, mi, 1); }
#pragma unroll
      for (int ni = 0; ni < 2; ++ni) { b01[ni][0] = rdB(p, ni, 0); b01[ni][1] = rdB(p, ni, 1); }
      __builtin_amdgcn_s_setprio(1);
#pragma unroll
      for (int mi = 0; mi < 4; ++mi)
#pragma unroll
        for (int ni = 0; ni < 2; ++ni) {
          acc[mi][ni] = __builtin_amdgcn_mfma_f32_16x16x32_bf16(a03[mi][0], b01[ni][0], acc[mi][ni], 0, 0, 0);
          acc[mi][ni] = __builtin_amdgcn_mfma_f32_16x16x32_bf16(a03[mi][1], b01[ni][1], acc[mi][ni], 0, 0, 0);
        }
      __builtin_amdgcn_s_setprio(0);
      // ph1
#pragma unroll
      for (int ni = 0; ni < 2; ++ni) { b23[ni][0] = rdB(p, ni + 2, 0); b23[ni][1] = rdB(p, ni + 2, 1); }
      __builtin_amdgcn_s_setprio(1);
#pragma unroll
      for (int mi = 0; mi < 4; ++mi)
#pragma unroll
        for (int ni = 0; ni < 2; ++ni) {
          acc[mi][ni + 2] = __builtin_amdgcn_mfma_f32_16x16x32_bf16(a03[mi][0], b23[ni][0], acc[mi][ni + 2], 0, 0, 0);
          acc[mi][ni + 2] = __builtin_amdgcn_mfma_f32_16x16x32_bf16(a03[mi][1], b23[ni][1], acc[mi][ni + 2], 0, 0, 0);
        }
      __builtin_amdgcn_s_setprio(0);
      // ph2
#pragma unroll
      for (int mi = 0; mi < 4; ++mi) { a47[mi][0] = rdA(p, mi + 4, 0); a47[mi][1] = rdA(p, mi + 4, 1); }
      __builtin_amdgcn_s_setprio(1);
#pragma unroll
      for (int mi = 0; mi < 4; ++mi)
#pragma unroll
        for (int ni = 0; ni < 2; ++ni) {
          acc[mi + 4][ni] = __builtin_amdgcn_mfma_f32_16x16x32_bf16(a47[mi][0], b01[ni][0], acc[mi + 4][ni], 0, 0, 0);
          acc[mi + 4][ni] = __builtin_amdgcn_mfma_f32_16x16x32_bf16(a47[mi][1], b01[ni][1], acc[mi + 4][ni], 0, 0, 0);
        }
      __builtin_amdgcn_s_setprio(0);
      WAIT_LGKM0;               // all buf-p reads retired (WAR)
      SB0; __builtin_amdgcn_s_barrier(); SB0;
      // ph3: stage kt+2 overlapped with final MFMA quadrant
      if (kt + 2 < 8) stage(kt + 2, p);
      __builtin_amdgcn_s_setprio(1);
#pragma unroll
      for (int mi = 0; mi < 4; ++mi)
#pragma unroll
        for (int ni = 0; ni < 2; ++ni) {
          acc[mi + 4][ni + 2] = __builtin_amdgcn_mfma_f32_16x16x32_bf16(a47[mi][0], b23[ni][0], acc[mi + 4][ni + 2], 0, 0, 0);
          acc[mi + 4][ni + 2] = __builtin_amdgcn_mfma_f32_16x16x32_bf16(a47[mi][1], b23[ni][1], acc[mi + 4][ni + 2], 0, 0, 0);
        }
      __builtin_amdgcn_s_setprio(0);
    }

    const int cc = lane & 15, cq = lane >> 4;
#pragma unroll
    for (int mi = 0; mi < 8; ++mi) {
#pragma unroll
      for (int ni = 0; ni < 4; ++ni) {
        const int gcol = bn0 + wn + ni * 16 + cc;
        const float bv = bcat[gcol];
#pragma unroll
        for (int rr = 0; rr < 4; ++rr) {
          const int grow = bm0 + wm + mi * 16 + cq * 4 + rr;
          qu[(size_t)grow * 2048 + gcol] = (__bf16)(acc[mi][ni][rr] + bv);
        }
      }
    }
  }
  __threadfence();
  gg.sync();

  // ================= stage 2: attention (2 units x 4 waves, 2 iters) ======
  // unit pairing shares qt -> identical ncl -> uniform barrier counts.
  {
    const int u = wave >> 2;          // sub-unit 0/1
    const int wv = wave & 3;          // wave-in-unit
    const int tu = t & 255;           // thread-in-unit
    char* ub = smem + u * 32768;
    __bf16* lK = (__bf16*)ub;                 // 8192 B, XOR-swizzled rows
    __bf16* lV = (__bf16*)(ub + 8192);        // 9216 B, V^T stride 72
    __bf16* Pb = (__bf16*)(ub + 17408);       // 9216 B, wave-local P
    const int cq = lane >> 4, cc = lane & 15;
    const int krow_st = tu >> 2, kgb = tu & 3;

    for (int i = 0; i < 2; ++i) {
      const int uid = i * 512 + blk * 2 + u;  // uid = qt*32 + h*4 + b
      const int qt = uid >> 5;
      const int h = (uid >> 2) & 7;
      const int b = uid & 3;
      const int q0 = qt * 64, qmax = q0 + 63;
      const size_t bL = (size_t)b * L_;

      bf16x8 aq0, aq1;
      {
        const __bf16* qsrc = qu + (bL + q0 + wv * 16 + cc) * QS + h * 64 + cq * 8;
        aq0 = *(const bf16x8*)qsrc;
        aq1 = *(const bf16x8*)(qsrc + 32);
      }

      float mreg[4], lreg[4];
#pragma unroll
      for (int rr = 0; rr < 4; ++rr) { mreg[rr] = -1e30f; lreg[rr] = 0.f; }
      f32x4 acc_o[4] = {};

      int clist[5]; int ncl = 0;
      clist[ncl++] = 0;
      if (qmax >= 64) clist[ncl++] = 64;
      {
        int lo = 1921 - q0; if (lo < 0) lo = 0; lo &= ~63;
        const int hik = min(qmax, 2048 - q0);
        for (int c = lo; c <= hik; c += 64)
          if (c >= 128) clist[ncl++] = c;
      }

      // prologue: tile-0 K/V into registers
      bf16x8 k0r, k1r, var, vbr;
      {
        const __bf16* src = qu + (bL + clist[0] + krow_st) * QS + 512 + h * 64;
        k0r = *(const bf16x8*)(src + kgb * 8);
        k1r = *(const bf16x8*)(src + kgb * 8 + 32);
        const __bf16* vsrc = qu + (bL + clist[0] + lane) * QS + 1024 + h * 64 + wv * 16;
        var = *(const bf16x8*)vsrc;
        vbr = *(const bf16x8*)(vsrc + 8);
      }

      for (int ci = 0; ci < ncl; ++ci) {
        const int c0 = clist[ci];
        WAIT_VM(0);                       // this tile's K/V landed
        SB0; __builtin_amdgcn_s_barrier(); SB0;   // WAR: prior reads done
        {
          char* lkb = (char*)lK;
          const int sw = (krow_st & 7) << 4;
          *(bf16x8*)(lkb + ((krow_st * 128 + kgb * 16) ^ sw))      = k0r;
          *(bf16x8*)(lkb + ((krow_st * 128 + kgb * 16 + 64) ^ sw)) = k1r;
#pragma unroll
          for (int e = 0; e < 8; ++e) {
            lV[(wv * 16 + e) * SP + lane]     = var[e];
            lV[(wv * 16 + 8 + e) * SP + lane] = vbr[e];
          }
        }
        if (ci + 1 < ncl) {               // issue next tile's loads
          const int cn = clist[ci + 1];
          const __bf16* src = qu + (bL + cn + krow_st) * QS + 512 + h * 64;
          k0r = *(const bf16x8*)(src + kgb * 8);
          k1r = *(const bf16x8*)(src + kgb * 8 + 32);
          const __bf16* vsrc = qu + (bL + cn + lane) * QS + 1024 + h * 64 + wv * 16;
          var = *(const bf16x8*)(vsrc);
          vbr = *(const bf16x8*)(vsrc + 8);
        }
        WAIT_LGKM0;                       // my ds_writes retired
        SB0; __builtin_amdgcn_s_barrier(); SB0;   // RAW: writes visible

        f32x4 s[4];
        {
          const char* lkb = (const char*)lK;
#pragma unroll
          for (int nt = 0; nt < 4; ++nt) {
            const int krow = nt * 16 + cc;
            const int sw = (krow & 7) << 4;
            bf16x8 bk0 = *(const bf16x8*)(lkb + ((krow * 128 + cq * 16) ^ sw));
            bf16x8 bk1 = *(const bf16x8*)(lkb + ((krow * 128 + 64 + cq * 16) ^ sw));
            f32x4 a = {};
            a = __builtin_amdgcn_mfma_f32_16x16x32_bf16(aq0, bk0, a, 0, 0, 0);
            a = __builtin_amdgcn_mfma_f32_16x16x32_bf16(aq1, bk1, a, 0, 0, 0);
            s[nt] = a;
          }
        }

#pragma unroll
        for (int nt = 0; nt < 4; ++nt) {
#pragma unroll
          for (int rr = 0; rr < 4; ++rr) {
            const int i2 = q0 + wv * 16 + cq * 4 + rr;
            const int j = c0 + nt * 16 + cc;
            const int ij = i2 + j;
            const bool valid = (j <= i2) &&
                ((ij >= 1984 && ij <= 2048) || (j <= 64 && ij <= 2048));
            s[nt][rr] = valid ? s[nt][rr] * 0.125f : -1e30f;
          }
        }

        f32x4 pm;
#pragma unroll
        for (int rr = 0; rr < 4; ++rr)
          pm[rr] = fmaxf(fmaxf(s[0][rr], s[1][rr]), fmaxf(s[2][rr], s[3][rr]));
#pragma unroll
        for (int m = 1; m < 16; m <<= 1) {
#pragma unroll
          for (int rr = 0; rr < 4; ++rr)
            pm[rr] = fmaxf(pm[rr], __shfl_xor(pm[rr], m, 64));
        }
        float corr[4];
#pragma unroll
        for (int rr = 0; rr < 4; ++rr) {
          const float nm = fmaxf(mreg[rr], pm[rr]);
          corr[rr] = __expf(mreg[rr] - nm);
          mreg[rr] = nm;
        }

        f32x4 ps = {};
#pragma unroll
        for (int nt = 0; nt < 4; ++nt) {
#pragma unroll
          for (int rr = 0; rr < 4; ++rr) {
            const float p = __expf(s[nt][rr] - mreg[rr]);
            ps[rr] += p;
            Pb[(wv * 16 + cq * 4 + rr) * SP + nt * 16 + cc] = (__bf16)p;
          }
        }
#pragma unroll
        for (int m = 1; m < 16; m <<= 1) {
#pragma unroll
          for (int rr = 0; rr < 4; ++rr)
            ps[rr] += __shfl_xor(ps[rr], m, 64);
        }
#pragma unroll
        for (int rr = 0; rr < 4; ++rr) lreg[rr] = lreg[rr] * corr[rr] + ps[rr];

        {
          bf16x8 pa0 = *(const bf16x8*)(Pb + (wv * 16 + cc) * SP + cq * 8);
          bf16x8 pa1 = *(const bf16x8*)(Pb + (wv * 16 + cc) * SP + 32 + cq * 8);
#pragma unroll
          for (int dt = 0; dt < 4; ++dt) {
#pragma unroll
            for (int rr = 0; rr < 4; ++rr) acc_o[dt][rr] *= corr[rr];
            bf16x8 vb0 = *(const bf16x8*)(lV + (dt * 16 + cc) * SP + cq * 8);
            bf16x8 vb1 = *(const bf16x8*)(lV + (dt * 16 + cc) * SP + 32 + cq * 8);
            acc_o[dt] = __builtin_amdgcn_mfma_f32_16x16x32_bf16(pa0, vb0, acc_o[dt], 0, 0, 0);
            acc_o[dt] = __builtin_amdgcn_mfma_f32_16x16x32_bf16(pa1, vb1, acc_o[dt], 0, 0, 0);
          }
        }
      }

#pragma unroll
      for (int dt = 0; dt < 4; ++dt) {
#pragma unroll
        for (int rr = 0; rr < 4; ++rr) {
          const int row16 = cq * 4 + rr;
          const size_t qrow = bL + q0 + wv * 16 + row16;
          const int d = dt * 16 + cc;
          const float o = acc_o[dt][rr] / fmaxf(lreg[rr], 1e-30f);
          const float uv = (float)qu[qrow * QS + 1536 + h * 64 + d];
          gb[qrow * D_ + h * 64 + d] = (__bf16)(o / (1.f + __expf(-o)) * uv);
        }
      }
    }
  }
  __threadfence();
  gg.sync();

  // ================= stage 3: out gemm, 128x128 pipelined (8 waves) =======
  // out[8192][512] = gb[8192][512] @ wob[512][512]^T + bo
  {
    const int bm0 = (blk & 63) * 128;
    const int bn0 = (blk >> 6) * 128;
    const int wm = (wave >> 2) * 64;
    const int wn = (wave & 3) * 32;
    const int r = lane & 15, q = lane >> 4;

    auto stg = [&](int kt, int p) {
#pragma unroll
      for (int j = 0; j < 2; ++j) {
        const int c = t + j * 512;
        const int row = c >> 3;
        const int cs = (c & 7) ^ (row & 7);
        gl16(gb + (size_t)(bm0 + row) * 512 + kt * 64 + cs * 8,
             (__bf16*)(smem + p * 16384) + c * 8);
      }
#pragma unroll
      for (int j = 0; j < 2; ++j) {
        const int c = t + j * 512;
        const int row = c >> 3;
        const int cs = (c & 7) ^ (row & 7);
        gl16(wob + (size_t)(bn0 + row) * 512 + kt * 64 + cs * 8,
             (__bf16*)(smem + 32768 + p * 16384) + c * 8);
      }
    };
    auto rA = [&](int p, int mi, int ks) -> bf16x8 {
      const int row = wm + mi * 16 + r;
      const int byte = row * 128 + ((ks * 64 + q * 16) ^ ((row & 7) << 4));
      return *(const bf16x8*)(smem + p * 16384 + byte);
    };
    auto rB = [&](int p, int ni, int ks) -> bf16x8 {
      const int row = wn + ni * 16 + r;
      const int byte = row * 128 + ((ks * 64 + q * 16) ^ ((row & 7) << 4));
      return *(const bf16x8*)(smem + 32768 + p * 16384 + byte);
    };

    f32x4 acc2[4][2] = {};
    WAIT_VM(0);
    stg(0, 0); stg(1, 1);

    for (int kt = 0; kt < 8; ++kt) {
      const int p = kt & 1;
      if (kt < 7) { WAIT_VM(4); } else { WAIT_VM(0); }
      SB0; __builtin_amdgcn_s_barrier(); SB0;
      bf16x8 af[4][2], bf[2][2];
#pragma unroll
      for (int mi = 0; mi < 4; ++mi) { af[mi][0] = rA(p, mi, 0); af[mi][1] = rA(p, mi, 1); }
#pragma unroll
      for (int ni = 0; ni < 2; ++ni) { bf[ni][0] = rB(p, ni, 0); bf[ni][1] = rB(p, ni, 1); }
      WAIT_LGKM0;
      SB0; __builtin_amdgcn_s_barrier(); SB0;      // WAR: all reads retired
      if (kt + 2 < 8) stg(kt + 2, p);
      __builtin_amdgcn_s_setprio(1);
#pragma unroll
      for (int mi = 0; mi < 4; ++mi)
#pragma unroll
        for (int ni = 0; ni < 2; ++ni) {
          acc2[mi][ni] = __builtin_amdgcn_mfma_f32_16x16x32_bf16(af[mi][0], bf[ni][0], acc2[mi][ni], 0, 0, 0);
          acc2[mi][ni] = __builtin_amdgcn_mfma_f32_16x16x32_bf16(af[mi][1], bf[ni][1], acc2[mi][ni], 0, 0, 0);
        }
      __builtin_amdgcn_s_setprio(0);
    }

    const int cc = lane & 15, cq = lane >> 4;
#pragma unroll
    for (int mi = 0; mi < 4; ++mi) {
#pragma unroll
      for (int ni = 0; ni < 2; ++ni) {
        const int gcol = bn0 + wn + ni * 16 + cc;
        const float bv = bo[gcol];
#pragma unroll
        for (int rr = 0; rr < 4; ++rr) {
          const int grow = bm0 + wm + mi * 16 + cq * 4 + rr;
          out[(size_t)grow * 512 + gcol] = acc2[mi][ni][rr] + bv;
        }
      }
    }
  }
}

// ===========================================================================
// Fallback path (current green 4-kernel pipeline) if cooperative launch is
// unavailable/uncapturable.
// ===========================================================================
__global__ __launch_bounds__(256) void cvt_pack(
    const float* __restrict__ x, const float* __restrict__ wq,
    const float* __restrict__ wu, const float* __restrict__ wo,
    const float* __restrict__ bq, const float* __restrict__ bu,
    __bf16* __restrict__ xb, __bf16* __restrict__ wcat,
    __bf16* __restrict__ wob, float* __restrict__ bcat)
{
  const int idx8 = blockIdx.x * 256 + threadIdx.x;
  const float* src; __bf16* dst; size_t so, dof;
  if (idx8 < 524288)      { src = x;  dst = xb;   so = (size_t)idx8 * 8;            dof = so; }
  else if (idx8 < 622592) { src = wq; dst = wcat; so = (size_t)(idx8 - 524288) * 8; dof = so; }
  else if (idx8 < 655360) { src = wu; dst = wcat; so = (size_t)(idx8 - 622592) * 8; dof = so + 786432; }
  else                    { src = wo; dst = wob;  so = (size_t)(idx8 - 655360) * 8; dof = so; }
  const float4 lo = *(const float4*)(src + so);
  const float4 hi = *(const float4*)(src + so + 4);
  bf16x8 r;
  r[0] = (__bf16)lo.x; r[1] = (__bf16)lo.y; r[2] = (__bf16)lo.z; r[3] = (__bf16)lo.w;
  r[4] = (__bf16)hi.x; r[5] = (__bf16)hi.y; r[6] = (__bf16)hi.z; r[7] = (__bf16)hi.w;
  *(bf16x8*)(dst + dof) = r;
  if (blockIdx.x == 0) {
#pragma unroll
    for (int e = 0; e < 8; ++e) {
      const int col = threadIdx.x * 8 + e;
      bcat[col] = (col < 1536) ? bq[col] : bu[col - 1536];
    }
  }
}

__global__ __launch_bounds__(512, 2) void gemm256(
    const __bf16* __restrict__ A, const __bf16* __restrict__ W,
    const float* __restrict__ bias, __bf16* __restrict__ C,
    int M, int N, int K)
{
  extern __shared__ char smem[];
  const int t = threadIdx.x;
  const int lane = t & 63;
  const int wave = t >> 6;
  const int wm = (wave >> 2) * 128;
  const int wn = (wave & 3) * 64;
  const int bm0 = blockIdx.x * 256;
  const int bn0 = blockIdx.y * 256;
  const int r = lane & 15, q = lane >> 4;
  const int nt = K >> 6;

  auto stage = [&](int kt, int p) {
#pragma unroll
    for (int j = 0; j < 4; ++j) {
      const int c = t + j * 512;
      const int row = c >> 3;
      const int cs = (c & 7) ^ (row & 7);
      gl16(A + (size_t)(bm0 + row) * K + kt * 64 + cs * 8,
           (__bf16*)(smem + p * 32768) + c * 8);
    }
#pragma unroll
    for (int j = 0; j < 4; ++j) {
      const int c = t + j * 512;
      const int row = c >> 3;
      const int cs = (c & 7) ^ (row & 7);
      gl16(W + (size_t)(bn0 + row) * K + kt * 64 + cs * 8,
           (__bf16*)(smem + 65536 + p * 32768) + c * 8);
    }
  };
  auto rdA = [&](int p, int mi, int ks) -> bf16x8 {
    const int row = wm + mi * 16 + r;
    const int byte = row * 128 + ((ks * 64 + q * 16) ^ ((row & 7) << 4));
    return *(const bf16x8*)(smem + p * 32768 + byte);
  };
  auto rdB = [&](int p, int ni, int ks) -> bf16x8 {
    const int row = wn + ni * 16 + r;
    const int byte = row * 128 + ((ks * 64 + q * 16) ^ ((row & 7) << 4));
    return *(const bf16x8*)(smem + 65536 + p * 32768 + byte);
  };

  f32x4 acc[8][4] = {};
  stage(0, 0);
  stage(1, 1);

  for (int kt = 0; kt < nt; ++kt) {
    const int p = kt & 1;
    if (kt < nt - 1) { WAIT_VM(8); } else { WAIT_VM(0); }
    SB0; __builtin_amdgcn_s_barrier(); SB0;

    bf16x8 a03[4][2], a47[4][2], b01[2][2], b23[2][2];
#pragma unroll
    for (int mi = 0; mi < 4; ++mi) { a03[mi][0] = rdA(p, mi, 0); a03[mi][1] = rdA(p, mi, 1); }
#pragma unroll
    for (int ni = 0; ni < 2; ++ni) { b01[ni][0] = rdB(p, ni, 0); b01[ni][1] = rdB(p, ni, 1); }
    __builtin_amdgcn_s_setprio(1);
#pragma unroll
    for (int mi = 0; mi < 4; ++mi)
#pragma unroll
      for (int ni = 0; ni < 2; ++ni) {
        acc[mi][ni] = __builtin_amdgcn_mfma_f32_16x16x32_bf16(a03[mi][0], b01[ni][0], acc[mi][ni], 0, 0, 0);
        acc[mi][ni] = __builtin_amdgcn_mfma_f32_16x16x32_bf16(a03[mi][1], b01[ni][1], acc[mi][ni], 0, 0, 0);
      }
    __builtin_amdgcn_s_setprio(0);
#pragma unroll
    for (int ni = 0; ni < 2; ++ni) { b23[ni][0] = rdB(p, ni + 2, 0); b23[ni][1] = rdB(p, ni + 2, 1); }
    __builtin_amdgcn_s_setprio(1);
#pragma unroll
    for (int mi = 0; mi < 4; ++mi)
#pragma unroll
      for (int ni = 0; ni < 2; ++ni) {
        acc[mi][ni + 2] = __builtin_amdgcn_mfma_f32_16x16x32_bf16(a03[mi][0], b23[ni][0], acc[mi][ni + 2], 0, 0, 0);
        acc[mi][ni + 2] = __builtin_amdgcn_mfma_f32_16x16x32_bf16(a03[mi][1], b23[ni][1], acc[mi][ni + 2], 0, 0, 0);
      }
    __builtin_amdgcn_s_setprio(0);
#pragma unroll
    for (int mi = 0; mi < 4; ++mi) { a47[mi][0] = rdA(p, mi + 4, 0); a47[mi][1] = rdA(p, mi + 4, 1); }
    __builtin_amdgcn_s_setprio(1);
#pragma unroll
    for (int mi = 0; mi < 4; ++mi)
#pragma unroll
      for (int ni = 0; ni < 2; ++ni) {
        acc[mi + 4][ni] = __builtin_amdgcn_mfma_f32_16x16x32_bf16(a47[mi][0], b01[ni][0], acc[mi + 4][ni], 0, 0, 0);
        acc[mi + 4][ni] = __builtin_amdgcn_mfma_f32_16x16x32_bf16(a47[mi][1], b01[ni][1], acc[mi + 4][ni], 0, 0, 0);
      }
    __builtin_amdgcn_s_setprio(0);
    WAIT_LGKM0;
    SB0; __builtin_amdgcn_s_barrier(); SB0;
    if (kt + 2 < nt) stage(kt + 2, p);
    __builtin_amdgcn_s_setprio(1);
#pragma unroll
    for (int mi = 0; mi < 4; ++mi)
#pragma unroll
      for (int ni = 0; ni < 2; ++ni) {
        acc[mi + 4][ni + 2] = __builtin_amdgcn_mfma_f32_16x16x32_bf16(a47[mi][0], b23[ni][0], acc[mi + 4][ni + 2], 0, 0, 0);
        acc[mi + 4][ni + 2] = __builtin_amdgcn_mfma_f32_16x16x32_bf16(a47[mi][1], b23[ni][1], acc[mi + 4][ni + 2], 0, 0, 0);
      }
    __builtin_amdgcn_s_setprio(0);
  }

  const int cc = lane & 15, cq = lane >> 4;
#pragma unroll
  for (int mi = 0; mi < 8; ++mi) {
#pragma unroll
    for (int ni = 0; ni < 4; ++ni) {
      const int gcol = bn0 + wn + ni * 16 + cc;
      const float bv = bias[gcol];
#pragma unroll
      for (int rr = 0; rr < 4; ++rr) {
        const int grow = bm0 + wm + mi * 16 + cq * 4 + rr;
        C[(size_t)grow * N + gcol] = (__bf16)(acc[mi][ni][rr] + bv);
      }
    }
  }
}

template <typename TOUT>
__global__ __launch_bounds__(256) void gemm_async(
    const __bf16* __restrict__ A, const __bf16* __restrict__ W,
    const float* __restrict__ bias, TOUT* __restrict__ C,
    int M, int N, int K)
{
  __shared__ __bf16 lA[4096];
  __shared__ __bf16 lB[4096];
  const int t = threadIdx.x;
  const int lane = t & 63;
  const int wave = t >> 6;
  const int bm0 = blockIdx.x * 128;
  const int bn0 = blockIdx.y * 128;
  const int wm = (wave >> 1) * 64;
  const int wn = (wave & 1) * 64;

  f32x4 acc[4][4] = {};

  const __bf16* Ap0 = A + (size_t)(bm0 + (t >> 2)) * K + (t & 3) * 8;
  const __bf16* Bp0 = W + (size_t)(bn0 + (t >> 2)) * K + (t & 3) * 8;
  const size_t r64 = (size_t)64 * K;

  for (int k0 = 0; k0 < K; k0 += 32) {
    __syncthreads();
    gl16(Ap0 + k0,       lA + t * 8);
    gl16(Ap0 + r64 + k0, lA + (t + 256) * 8);
    gl16(Bp0 + k0,       lB + t * 8);
    gl16(Bp0 + r64 + k0, lB + (t + 256) * 8);
    __syncthreads();

    const int r = lane & 15, q = lane >> 4;
    bf16x8 af[4], bfr[4];
#pragma unroll
    for (int mi = 0; mi < 4; ++mi) af[mi] = ((const bf16x8*)lA)[(wm + mi * 16 + r) * 4 + q];
#pragma unroll
    for (int ni = 0; ni < 4; ++ni) bfr[ni] = ((const bf16x8*)lB)[(wn + ni * 16 + r) * 4 + q];
#pragma unroll
    for (int mi = 0; mi < 4; ++mi)
#pragma unroll
      for (int ni = 0; ni < 4; ++ni)
        acc[mi][ni] = __builtin_amdgcn_mfma_f32_16x16x32_bf16(af[mi], bfr[ni], acc[mi][ni], 0, 0, 0);
  }

  const int cc = lane & 15, cq = lane >> 4;
#pragma unroll
  for (int mi = 0; mi < 4; ++mi) {
#pragma unroll
    for (int ni = 0; ni < 4; ++ni) {
      const int gcol = bn0 + wn + ni * 16 + cc;
      const float bv = bias[gcol];
#pragma unroll
      for (int rr = 0; rr < 4; ++rr) {
        const int grow = bm0 + wm + mi * 16 + cq * 4 + rr;
        C[(size_t)grow * N + gcol] = (TOUT)(acc[mi][ni][rr] + bv);
      }
    }
  }
}

__global__ __launch_bounds__(256) void attn_tile(
    const __bf16* __restrict__ qu, __bf16* __restrict__ g)
{
  const int qt = blockIdx.x, h = blockIdx.y, b = blockIdx.z;
  const int t = threadIdx.x;
  const int lane = t & 63;
  const int w = t >> 6;
  const int q0 = qt * 64, qmax = q0 + 63;
  const size_t bL = (size_t)b * L_;

  __shared__ __bf16 lK[4096];
  __shared__ __bf16 lV[64 * SP];
  __shared__ __bf16 Pb[64 * SP];

  const int cq = lane >> 4, cc = lane & 15;
  const int krow_st = t >> 2, kgb = t & 3;

  bf16x8 aq0, aq1;
  {
    const __bf16* qsrc = qu + (bL + q0 + w * 16 + cc) * QS + h * 64 + cq * 8;
    aq0 = *(const bf16x8*)qsrc;
    aq1 = *(const bf16x8*)(qsrc + 32);
  }

  float mreg[4], lreg[4];
#pragma unroll
  for (int rr = 0; rr < 4; ++rr) { mreg[rr] = -1e30f; lreg[rr] = 0.f; }
  f32x4 acc_o[4] = {};

  int clist[5]; int ncl = 0;
  clist[ncl++] = 0;
  if (qmax >= 64) clist[ncl++] = 64;
  {
    int lo = 1921 - q0; if (lo < 0) lo = 0; lo &= ~63;
    const int hik = min(qmax, 2048 - q0);
    for (int c = lo; c <= hik; c += 64)
      if (c >= 128) clist[ncl++] = c;
  }

  bf16x8 k0r, k1r, var, vbr;
  {
    const __bf16* src = qu + (bL + clist[0] + krow_st) * QS + 512 + h * 64;
    k0r = *(const bf16x8*)(src + kgb * 8);
    k1r = *(const bf16x8*)(src + kgb * 8 + 32);
    const __bf16* vsrc = qu + (bL + clist[0] + lane) * QS + 1024 + h * 64 + w * 16;
    var = *(const bf16x8*)vsrc;
    vbr = *(const bf16x8*)(vsrc + 8);
  }

  for (int ci = 0; ci < ncl; ++ci) {
    const int c0 = clist[ci];
    WAIT_VM(0);
    SB0; __builtin_amdgcn_s_barrier(); SB0;
    {
      char* lkb = (char*)lK;
      const int sw = (krow_st & 7) << 4;
      *(bf16x8*)(lkb + ((krow_st * 128 + kgb * 16) ^ sw))      = k0r;
      *(bf16x8*)(lkb + ((krow_st * 128 + kgb * 16 + 64) ^ sw)) = k1r;
#pragma unroll
      for (int e = 0; e < 8; ++e) {
        lV[(w * 16 + e) * SP + lane]     = var[e];
        lV[(w * 16 + 8 + e) * SP + lane] = vbr[e];
      }
    }
    if (ci + 1 < ncl) {
      const int cn = clist[ci + 1];
      const __bf16* src = qu + (bL + cn + krow_st) * QS + 512 + h * 64;
      k0r = *(const bf16x8*)(src + kgb * 8);
      k1r = *(const bf16x8*)(src + kgb * 8 + 32);
      const __bf16* vsrc = qu + (bL + cn + lane) * QS + 1024 + h * 64 + w * 16;
      var = *(const bf16x8*)(vsrc);
      vbr = *(const bf16x8*)(vsrc + 8);
    }
    WAIT_LGKM0;
    SB0; __builtin_amdgcn_s_barrier(); SB0;

    f32x4 s[4];
    {
      const char* lkb = (const char*)lK;
#pragma unroll
      for (int nt = 0; nt < 4; ++nt) {
        const int krow = nt * 16 + cc;
        const int sw = (krow & 7) << 4;
        bf16x8 bk0 = *(const bf16x8*)(lkb + ((krow * 128 + cq * 16) ^ sw));
        bf16x8 bk1 = *(const bf16x8*)(lkb + ((krow * 128 + 64 + cq * 16) ^ sw));
        f32x4 a = {};
        a = __builtin_amdgcn_mfma_f32_16x16x32_bf16(aq0, bk0, a, 0, 0, 0);
        a = __builtin_amdgcn_mfma_f32_16x16x32_bf16(aq1, bk1, a, 0, 0, 0);
        s[nt] = a;
      }
    }

#pragma unroll
    for (int nt = 0; nt < 4; ++nt) {
#pragma unroll
      for (int rr = 0; rr < 4; ++rr) {
        const int i = q0 + w * 16 + cq * 4 + rr;
        const int j = c0 + nt * 16 + cc;
        const int ij = i + j;
        const bool valid = (j <= i) &&
            ((ij >= 1984 && ij <= 2048) || (j <= 64 && ij <= 2048));
        s[nt][rr] = valid ? s[nt][rr] * 0.125f : -1e30f;
      }
    }

    f32x4 pm;
#pragma unroll
    for (int rr = 0; rr < 4; ++rr)
      pm[rr] = fmaxf(fmaxf(s[0][rr], s[1][rr]), fmaxf(s[2][rr], s[3][rr]));
#pragma unroll
    for (int m = 1; m < 16; m <<= 1) {
#pragma unroll
      for (int rr = 0; rr < 4; ++rr)
        pm[rr] = fmaxf(pm[rr], __shfl_xor(pm[rr], m, 64));
    }
    float corr[4];
#pragma unroll
    for (int rr = 0; rr < 4; ++rr) {
      const float nm = fmaxf(mreg[rr], pm[rr]);
      corr[rr] = __expf(mreg[rr] - nm);
      mreg[rr] = nm;
    }

    f32x4 ps = {};
#pragma unroll
    for (int nt = 0; nt < 4; ++nt) {
#pragma unroll
      for (int rr = 0; rr < 4; ++rr) {
        const float p = __expf(s[nt][rr] - mreg[rr]);
        ps[rr] += p;
        Pb[(w * 16 + cq * 4 + rr) * SP + nt * 16 + cc] = (__bf16)p;
      }
    }
#pragma unroll
    for (int m = 1; m < 16; m <<= 1) {
#pragma unroll
      for (int rr = 0; rr < 4; ++rr)
        ps[rr] += __shfl_xor(ps[rr], m, 64);
    }
#pragma unroll
    for (int rr = 0; rr < 4; ++rr) lreg[rr] = lreg[rr] * corr[rr] + ps[rr];

    {
      bf16x8 pa0 = *(const bf16x8*)(Pb + (w * 16 + cc) * SP + cq * 8);
      bf16x8 pa1 = *(const bf16x8*)(Pb + (w * 16 + cc) * SP + 32 + cq * 8);
#pragma unroll
      for (int dt = 0; dt < 4; ++dt) {
#pragma unroll
        for (int rr = 0; rr < 4; ++rr) acc_o[dt][rr] *= corr[rr];
        bf16x8 vb0 = *(const bf16x8*)(lV + (dt * 16 + cc) * SP + cq * 8);
        bf16x8 vb1 = *(const bf16x8*)(lV + (dt * 16 + cc) * SP + 32 + cq * 8);
        acc_o[dt] = __builtin_amdgcn_mfma_f32_16x16x32_bf16(pa0, vb0, acc_o[dt], 0, 0, 0);
        acc_o[dt] = __builtin_amdgcn_mfma_f32_16x16x32_bf16(pa1, vb1, acc_o[dt], 0, 0, 0);
      }
    }
  }

#pragma unroll
  for (int dt = 0; dt < 4; ++dt) {
#pragma unroll
    for (int rr = 0; rr < 4; ++rr) {
      const int row16 = cq * 4 + rr;
      const size_t qrow = bL + q0 + w * 16 + row16;
      const int d = dt * 16 + cc;
      const float o = acc_o[dt][rr] / fmaxf(lreg[rr], 1e-30f);
      const float uv = (float)qu[qrow * QS + 1536 + h * 64 + d];
      g[qrow * D_ + h * 64 + d] = (__bf16)(o / (1.f + __expf(-o)) * uv);
    }
  }
}

extern "C" void kernel_launch(void* const* d_in, const int* in_sizes, int n_in,
                              void* d_out, int out_size, void* d_ws, size_t ws_size,
                              hipStream_t stream) {
  const float* x     = (const float*)d_in[0];
  const float* w_qkv = (const float*)d_in[1];
  const float* b_qkv = (const float*)d_in[2];
  const float* w_u   = (const float*)d_in[3];
  const float* b_u   = (const float*)d_in[4];
  const float* w_out = (const float*)d_in[5];
  const float* b_out = (const float*)d_in[6];
  float* out = (float*)d_out;

  char* ws = (char*)d_ws;
  __bf16* xb   = (__bf16*)ws;                           //  8 MB
  __bf16* wcat = (__bf16*)(ws + 8388608);               //  2 MB [w_qkv;w_u]
  __bf16* wob  = (__bf16*)(ws + 10485760);              //  0.5 MB
  float*  bcat = (float*) (ws + 11010048);              //  8 KB
  __bf16* qu   = (__bf16*)(ws + 11018240);              // 32 MB [q|k|v|u]
  __bf16* gb   = (__bf16*)(ws + 44572672);              //  8 MB

  static int coop = -1;
  if (coop < 0) {
    hipFuncSetAttribute((const void*)mega,
                        hipFuncAttributeMaxDynamicSharedMemorySize, 131072);
    hipFuncSetAttribute((const void*)gemm256,
                        hipFuncAttributeMaxDynamicSharedMemorySize, 131072);
    int dev = 0; hipGetDevice(&dev);
    int v = 0;
    hipDeviceGetAttribute(&v, hipDeviceAttributeCooperativeLaunch, dev);
    coop = v;
  }

  bool done = false;
  if (coop > 0) {
    void* kargs[] = {(void*)&x, (void*)&w_qkv, (void*)&w_u, (void*)&w_out,
                     (void*)&b_qkv, (void*)&b_u, (void*)&b_out,
                     (void*)&xb, (void*)&wcat, (void*)&wob, (void*)&bcat,
                     (void*)&qu, (void*)&gb, (void*)&out};
    if (hipLaunchCooperativeKernel((void*)mega, dim3(256), dim3(512),
                                   kargs, 131072, stream) == hipSuccess) {
      done = true;
    } else {
      (void)hipGetLastError();   // clear sticky error before fallback
    }
  }
  if (!done) {
    cvt_pack<<<dim3(2688), dim3(256), 0, stream>>>(
        x, w_qkv, w_u, w_out, b_qkv, b_u, xb, wcat, wob, bcat);
    gemm256<<<dim3(32, 8), dim3(512), 131072, stream>>>(
        xb, wcat, bcat, qu, 8192, 2048, 512);
    attn_tile<<<dim3(L_ / 64, H_, B_), dim3(256), 0, stream>>>(qu, gb);
    gemm_async<float><<<dim3(64, 4), dim3(256), 0, stream>>>(
        gb, wob, b_out, out, 8192, 512, 512);
  }
}

// Round 5
// 147.847 us; speedup vs baseline: 2.8137x; 2.8137x over previous
//
#include <hip/hip_runtime.h>
#include <hip/hip_bf16.h>

typedef __bf16 bf16x8 __attribute__((ext_vector_type(8)));
typedef float f32x4 __attribute__((ext_vector_type(4)));

#define B_ 4
#define L_ 2048
#define D_ 512
#define H_ 8
#define QS 2048
#define SP 72

#define SB0 __builtin_amdgcn_sched_barrier(0)
#define WAIT_VM(n) asm volatile("s_waitcnt vmcnt(" #n ")" ::: "memory")
#define WAIT_LGKM0 asm volatile("s_waitcnt lgkmcnt(0)" ::: "memory")

// async 16B global -> LDS (gfx950 global_load_lds_dwordx4)
__device__ __forceinline__ void gl16(const __bf16* g, __bf16* l) {
  __builtin_amdgcn_global_load_lds(
      (const __attribute__((address_space(1))) void*)g,
      (__attribute__((address_space(3))) void*)l, 16, 0, 0);
}

// f32 -> bf16 conversion + packing. vec8 regions:
// x[0,524288) wqkv[524288,622592) wu[622592,655360) wout[655360,688128)
// Also builds bcat[2048] = [b_qkv ; b_u] (f32) in block 0.
__global__ __launch_bounds__(256) void cvt_pack(
    const float* __restrict__ x, const float* __restrict__ wq,
    const float* __restrict__ wu, const float* __restrict__ wo,
    const float* __restrict__ bq, const float* __restrict__ bu,
    __bf16* __restrict__ xb, __bf16* __restrict__ wcat,
    __bf16* __restrict__ wob, float* __restrict__ bcat)
{
  const int idx8 = blockIdx.x * 256 + threadIdx.x;
  const float* src; __bf16* dst; size_t so, dof;
  if (idx8 < 524288)      { src = x;  dst = xb;   so = (size_t)idx8 * 8;            dof = so; }
  else if (idx8 < 622592) { src = wq; dst = wcat; so = (size_t)(idx8 - 524288) * 8; dof = so; }
  else if (idx8 < 655360) { src = wu; dst = wcat; so = (size_t)(idx8 - 622592) * 8; dof = so + 786432; }
  else                    { src = wo; dst = wob;  so = (size_t)(idx8 - 655360) * 8; dof = so; }
  const float4 lo = *(const float4*)(src + so);
  const float4 hi = *(const float4*)(src + so + 4);
  bf16x8 r;
  r[0] = (__bf16)lo.x; r[1] = (__bf16)lo.y; r[2] = (__bf16)lo.z; r[3] = (__bf16)lo.w;
  r[4] = (__bf16)hi.x; r[5] = (__bf16)hi.y; r[6] = (__bf16)hi.z; r[7] = (__bf16)hi.w;
  *(bf16x8*)(dst + dof) = r;
  if (blockIdx.x == 0) {
#pragma unroll
    for (int e = 0; e < 8; ++e) {
      const int col = threadIdx.x * 8 + e;
      bcat[col] = (col < 1536) ? bq[col] : bu[col - 1536];
    }
  }
}

// ---------------------------------------------------------------------------
// 256x256 deep-pipelined GEMM (T2+T3+T4+T5), r2/r3-green structure.
// ---------------------------------------------------------------------------
__global__ __launch_bounds__(512, 2) void gemm256(
    const __bf16* __restrict__ A, const __bf16* __restrict__ W,
    const float* __restrict__ bias, __bf16* __restrict__ C,
    int M, int N, int K)
{
  extern __shared__ char smem[];
  const int t = threadIdx.x;
  const int lane = t & 63;
  const int wave = t >> 6;
  const int wm = (wave >> 2) * 128;
  const int wn = (wave & 3) * 64;
  const int bm0 = blockIdx.x * 256;
  const int bn0 = blockIdx.y * 256;
  const int r = lane & 15, q = lane >> 4;
  const int nt = K >> 6;

  auto stage = [&](int kt, int p) {
#pragma unroll
    for (int j = 0; j < 4; ++j) {
      const int c = t + j * 512;
      const int row = c >> 3;
      const int cs = (c & 7) ^ (row & 7);
      gl16(A + (size_t)(bm0 + row) * K + kt * 64 + cs * 8,
           (__bf16*)(smem + p * 32768) + c * 8);
    }
#pragma unroll
    for (int j = 0; j < 4; ++j) {
      const int c = t + j * 512;
      const int row = c >> 3;
      const int cs = (c & 7) ^ (row & 7);
      gl16(W + (size_t)(bn0 + row) * K + kt * 64 + cs * 8,
           (__bf16*)(smem + 65536 + p * 32768) + c * 8);
    }
  };
  auto rdA = [&](int p, int mi, int ks) -> bf16x8 {
    const int row = wm + mi * 16 + r;
    const int byte = row * 128 + ((ks * 64 + q * 16) ^ ((row & 7) << 4));
    return *(const bf16x8*)(smem + p * 32768 + byte);
  };
  auto rdB = [&](int p, int ni, int ks) -> bf16x8 {
    const int row = wn + ni * 16 + r;
    const int byte = row * 128 + ((ks * 64 + q * 16) ^ ((row & 7) << 4));
    return *(const bf16x8*)(smem + 65536 + p * 32768 + byte);
  };

  f32x4 acc[8][4] = {};
  stage(0, 0);
  stage(1, 1);

  for (int kt = 0; kt < nt; ++kt) {
    const int p = kt & 1;
    if (kt < nt - 1) { WAIT_VM(8); } else { WAIT_VM(0); }
    SB0; __builtin_amdgcn_s_barrier(); SB0;

    bf16x8 a03[4][2], a47[4][2], b01[2][2], b23[2][2];
#pragma unroll
    for (int mi = 0; mi < 4; ++mi) { a03[mi][0] = rdA(p, mi, 0); a03[mi][1] = rdA(p, mi, 1); }
#pragma unroll
    for (int ni = 0; ni < 2; ++ni) { b01[ni][0] = rdB(p, ni, 0); b01[ni][1] = rdB(p, ni, 1); }
    __builtin_amdgcn_s_setprio(1);
#pragma unroll
    for (int mi = 0; mi < 4; ++mi)
#pragma unroll
      for (int ni = 0; ni < 2; ++ni) {
        acc[mi][ni] = __builtin_amdgcn_mfma_f32_16x16x32_bf16(a03[mi][0], b01[ni][0], acc[mi][ni], 0, 0, 0);
        acc[mi][ni] = __builtin_amdgcn_mfma_f32_16x16x32_bf16(a03[mi][1], b01[ni][1], acc[mi][ni], 0, 0, 0);
      }
    __builtin_amdgcn_s_setprio(0);
#pragma unroll
    for (int ni = 0; ni < 2; ++ni) { b23[ni][0] = rdB(p, ni + 2, 0); b23[ni][1] = rdB(p, ni + 2, 1); }
    __builtin_amdgcn_s_setprio(1);
#pragma unroll
    for (int mi = 0; mi < 4; ++mi)
#pragma unroll
      for (int ni = 0; ni < 2; ++ni) {
        acc[mi][ni + 2] = __builtin_amdgcn_mfma_f32_16x16x32_bf16(a03[mi][0], b23[ni][0], acc[mi][ni + 2], 0, 0, 0);
        acc[mi][ni + 2] = __builtin_amdgcn_mfma_f32_16x16x32_bf16(a03[mi][1], b23[ni][1], acc[mi][ni + 2], 0, 0, 0);
      }
    __builtin_amdgcn_s_setprio(0);
#pragma unroll
    for (int mi = 0; mi < 4; ++mi) { a47[mi][0] = rdA(p, mi + 4, 0); a47[mi][1] = rdA(p, mi + 4, 1); }
    __builtin_amdgcn_s_setprio(1);
#pragma unroll
    for (int mi = 0; mi < 4; ++mi)
#pragma unroll
      for (int ni = 0; ni < 2; ++ni) {
        acc[mi + 4][ni] = __builtin_amdgcn_mfma_f32_16x16x32_bf16(a47[mi][0], b01[ni][0], acc[mi + 4][ni], 0, 0, 0);
        acc[mi + 4][ni] = __builtin_amdgcn_mfma_f32_16x16x32_bf16(a47[mi][1], b01[ni][1], acc[mi + 4][ni], 0, 0, 0);
      }
    __builtin_amdgcn_s_setprio(0);
    WAIT_LGKM0;                 // all buf-p reads retired (WAR)
    SB0; __builtin_amdgcn_s_barrier(); SB0;
    if (kt + 2 < nt) stage(kt + 2, p);
    __builtin_amdgcn_s_setprio(1);
#pragma unroll
    for (int mi = 0; mi < 4; ++mi)
#pragma unroll
      for (int ni = 0; ni < 2; ++ni) {
        acc[mi + 4][ni + 2] = __builtin_amdgcn_mfma_f32_16x16x32_bf16(a47[mi][0], b23[ni][0], acc[mi + 4][ni + 2], 0, 0, 0);
        acc[mi + 4][ni + 2] = __builtin_amdgcn_mfma_f32_16x16x32_bf16(a47[mi][1], b23[ni][1], acc[mi + 4][ni + 2], 0, 0, 0);
      }
    __builtin_amdgcn_s_setprio(0);
  }

  const int cc = lane & 15, cq = lane >> 4;
#pragma unroll
  for (int mi = 0; mi < 8; ++mi) {
#pragma unroll
    for (int ni = 0; ni < 4; ++ni) {
      const int gcol = bn0 + wn + ni * 16 + cc;
      const float bv = bias[gcol];
#pragma unroll
      for (int rr = 0; rr < 4; ++rr) {
        const int grow = bm0 + wm + mi * 16 + cq * 4 + rr;
        C[(size_t)grow * N + gcol] = (__bf16)(acc[mi][ni][rr] + bv);
      }
    }
  }
}

// C[M,N] = A[M,K] @ W[N,K]^T + bias[N]; m97 128x128 structure (out-proj).
template <typename TOUT>
__global__ __launch_bounds__(256) void gemm_async(
    const __bf16* __restrict__ A, const __bf16* __restrict__ W,
    const float* __restrict__ bias, TOUT* __restrict__ C,
    int M, int N, int K)
{
  __shared__ __bf16 lA[4096];
  __shared__ __bf16 lB[4096];
  const int t = threadIdx.x;
  const int lane = t & 63;
  const int wave = t >> 6;
  const int bm0 = blockIdx.x * 128;
  const int bn0 = blockIdx.y * 128;
  const int wm = (wave >> 1) * 64;
  const int wn = (wave & 1) * 64;

  f32x4 acc[4][4] = {};

  const __bf16* Ap0 = A + (size_t)(bm0 + (t >> 2)) * K + (t & 3) * 8;
  const __bf16* Bp0 = W + (size_t)(bn0 + (t >> 2)) * K + (t & 3) * 8;
  const size_t r64 = (size_t)64 * K;

  for (int k0 = 0; k0 < K; k0 += 32) {
    __syncthreads();
    gl16(Ap0 + k0,       lA + t * 8);
    gl16(Ap0 + r64 + k0, lA + (t + 256) * 8);
    gl16(Bp0 + k0,       lB + t * 8);
    gl16(Bp0 + r64 + k0, lB + (t + 256) * 8);
    __syncthreads();

    const int r = lane & 15, q = lane >> 4;
    bf16x8 af[4], bfr[4];
#pragma unroll
    for (int mi = 0; mi < 4; ++mi) af[mi] = ((const bf16x8*)lA)[(wm + mi * 16 + r) * 4 + q];
#pragma unroll
    for (int ni = 0; ni < 4; ++ni) bfr[ni] = ((const bf16x8*)lB)[(wn + ni * 16 + r) * 4 + q];
#pragma unroll
    for (int mi = 0; mi < 4; ++mi)
#pragma unroll
      for (int ni = 0; ni < 4; ++ni)
        acc[mi][ni] = __builtin_amdgcn_mfma_f32_16x16x32_bf16(af[mi], bfr[ni], acc[mi][ni], 0, 0, 0);
  }

  const int cc = lane & 15, cq = lane >> 4;
#pragma unroll
  for (int mi = 0; mi < 4; ++mi) {
#pragma unroll
    for (int ni = 0; ni < 4; ++ni) {
      const int gcol = bn0 + wn + ni * 16 + cc;
      const float bv = bias[gcol];
#pragma unroll
      for (int rr = 0; rr < 4; ++rr) {
        const int grow = bm0 + wm + mi * 16 + cq * 4 + rr;
        C[(size_t)grow * N + gcol] = (TOUT)(acc[mi][ni][rr] + bv);
      }
    }
  }
}

// Flash-style MFMA attention, QBLK=128 / 512 threads / 8 waves.
// Per-wave code identical to the r1-green 4-wave version (each wave owns 16
// q-rows, w in [0,8)); merging two q-tiles per block cuts total K/V staged
// tiles ~35% (band tiles shared across 128 rows), halves block count and
// prologue/epilogue cost. Extra fully-masked band tiles for some rows are
// exact no-ops (pm=-1e30 -> corr=1, p=0) => bit-identical output.
__global__ __launch_bounds__(512) void attn_tile(
    const __bf16* __restrict__ qu,   // [B*L][2048]  q|k|v|u
    __bf16* __restrict__ g)          // [B*L][512]
{
  const int qt = blockIdx.x, h = blockIdx.y, b = blockIdx.z;
  const int t = threadIdx.x;
  const int lane = t & 63;
  const int w = t >> 6;                    // 8 waves, 16 q-rows each
  const int q0 = qt * 128, qmax = q0 + 127;
  const size_t bL = (size_t)b * L_;

  __shared__ __bf16 lK[4096];        // [64][64] bf16, XOR-swizzled rows (8KB)
  __shared__ __bf16 lV[64 * SP];     // V^T: [d 64][key 64] stride 72 (9KB)
  __shared__ __bf16 Pb[128 * SP];    // P: [q 128][key 64] stride 72 (18KB)

  const int cq = lane >> 4, cc = lane & 15;
  const int krow_st = t >> 3, kgb8 = t & 7;   // K-staging: 64 rows x 8 chunks

  bf16x8 aq0, aq1;
  {
    const __bf16* qsrc = qu + (bL + q0 + w * 16 + cc) * QS + h * 64 + cq * 8;
    aq0 = *(const bf16x8*)qsrc;
    aq1 = *(const bf16x8*)(qsrc + 32);
  }

  float mreg[4], lreg[4];
#pragma unroll
  for (int rr = 0; rr < 4; ++rr) { mreg[rr] = -1e30f; lreg[rr] = 0.f; }
  f32x4 acc_o[4] = {};

  int clist[8]; int ncl = 0;
  clist[ncl++] = 0;
  if (qmax >= 64) clist[ncl++] = 64;
  {
    int lo = 1984 - qmax; if (lo < 0) lo = 0; lo &= ~63;
    const int hik = min(qmax, 2048 - q0);
    for (int c = lo; c <= hik; c += 64)
      if (c >= 128) clist[ncl++] = c;
  }

  // prologue: tile-0 K/V into registers (T14 pipeline)
  bf16x8 k0r, var;
  {
    const __bf16* src = qu + (bL + clist[0] + krow_st) * QS + 512 + h * 64;
    k0r = *(const bf16x8*)(src + kgb8 * 8);
    const __bf16* vsrc = qu + (bL + clist[0] + lane) * QS + 1024 + h * 64 + w * 8;
    var = *(const bf16x8*)vsrc;
  }

  for (int ci = 0; ci < ncl; ++ci) {
    const int c0 = clist[ci];
    WAIT_VM(0);                                 // this tile's K/V landed
    SB0; __builtin_amdgcn_s_barrier(); SB0;     // WAR: prior tile's reads done
    {
      char* lkb = (char*)lK;
      const int sw = (krow_st & 7) << 4;
      *(bf16x8*)(lkb + ((krow_st * 128 + kgb8 * 16) ^ sw)) = k0r;
#pragma unroll
      for (int e = 0; e < 8; ++e)
        lV[(w * 8 + e) * SP + lane] = var[e];
    }
    if (ci + 1 < ncl) {                         // issue next tile's loads
      const int cn = clist[ci + 1];
      const __bf16* src = qu + (bL + cn + krow_st) * QS + 512 + h * 64;
      k0r = *(const bf16x8*)(src + kgb8 * 8);
      const __bf16* vsrc = qu + (bL + cn + lane) * QS + 1024 + h * 64 + w * 8;
      var = *(const bf16x8*)vsrc;
    }
    WAIT_LGKM0;                                 // my ds_writes retired
    SB0; __builtin_amdgcn_s_barrier(); SB0;     // RAW: all writes visible

    f32x4 s[4];
    {
      const char* lkb = (const char*)lK;
#pragma unroll
      for (int nt = 0; nt < 4; ++nt) {
        const int krow = nt * 16 + cc;
        const int sw = (krow & 7) << 4;
        bf16x8 bk0 = *(const bf16x8*)(lkb + ((krow * 128 + cq * 16) ^ sw));
        bf16x8 bk1 = *(const bf16x8*)(lkb + ((krow * 128 + 64 + cq * 16) ^ sw));
        f32x4 a = {};
        a = __builtin_amdgcn_mfma_f32_16x16x32_bf16(aq0, bk0, a, 0, 0, 0);
        a = __builtin_amdgcn_mfma_f32_16x16x32_bf16(aq1, bk1, a, 0, 0, 0);
        s[nt] = a;
      }
    }

#pragma unroll
    for (int nt = 0; nt < 4; ++nt) {
#pragma unroll
      for (int rr = 0; rr < 4; ++rr) {
        const int i = q0 + w * 16 + cq * 4 + rr;
        const int j = c0 + nt * 16 + cc;
        const int ij = i + j;
        const bool valid = (j <= i) &&
            ((ij >= 1984 && ij <= 2048) || (j <= 64 && ij <= 2048));
        s[nt][rr] = valid ? s[nt][rr] * 0.125f : -1e30f;
      }
    }

    f32x4 pm;
#pragma unroll
    for (int rr = 0; rr < 4; ++rr)
      pm[rr] = fmaxf(fmaxf(s[0][rr], s[1][rr]), fmaxf(s[2][rr], s[3][rr]));
#pragma unroll
    for (int m = 1; m < 16; m <<= 1) {
#pragma unroll
      for (int rr = 0; rr < 4; ++rr)
        pm[rr] = fmaxf(pm[rr], __shfl_xor(pm[rr], m, 64));
    }
    float corr[4];
#pragma unroll
    for (int rr = 0; rr < 4; ++rr) {
      const float nm = fmaxf(mreg[rr], pm[rr]);
      corr[rr] = __expf(mreg[rr] - nm);
      mreg[rr] = nm;
    }

    f32x4 ps = {};
#pragma unroll
    for (int nt = 0; nt < 4; ++nt) {
#pragma unroll
      for (int rr = 0; rr < 4; ++rr) {
        const float p = __expf(s[nt][rr] - mreg[rr]);
        ps[rr] += p;
        Pb[(w * 16 + cq * 4 + rr) * SP + nt * 16 + cc] = (__bf16)p;
      }
    }
#pragma unroll
    for (int m = 1; m < 16; m <<= 1) {
#pragma unroll
      for (int rr = 0; rr < 4; ++rr)
        ps[rr] += __shfl_xor(ps[rr], m, 64);
    }
#pragma unroll
    for (int rr = 0; rr < 4; ++rr) lreg[rr] = lreg[rr] * corr[rr] + ps[rr];

    {
      bf16x8 pa0 = *(const bf16x8*)(Pb + (w * 16 + cc) * SP + cq * 8);
      bf16x8 pa1 = *(const bf16x8*)(Pb + (w * 16 + cc) * SP + 32 + cq * 8);
#pragma unroll
      for (int dt = 0; dt < 4; ++dt) {
#pragma unroll
        for (int rr = 0; rr < 4; ++rr) acc_o[dt][rr] *= corr[rr];
        bf16x8 vb0 = *(const bf16x8*)(lV + (dt * 16 + cc) * SP + cq * 8);
        bf16x8 vb1 = *(const bf16x8*)(lV + (dt * 16 + cc) * SP + 32 + cq * 8);
        acc_o[dt] = __builtin_amdgcn_mfma_f32_16x16x32_bf16(pa0, vb0, acc_o[dt], 0, 0, 0);
        acc_o[dt] = __builtin_amdgcn_mfma_f32_16x16x32_bf16(pa1, vb1, acc_o[dt], 0, 0, 0);
      }
    }
  }

  // epilogue: register state only
#pragma unroll
  for (int dt = 0; dt < 4; ++dt) {
#pragma unroll
    for (int rr = 0; rr < 4; ++rr) {
      const int row16 = cq * 4 + rr;
      const size_t qrow = bL + q0 + w * 16 + row16;
      const int d = dt * 16 + cc;
      const float o = acc_o[dt][rr] / fmaxf(lreg[rr], 1e-30f);
      const float uv = (float)qu[qrow * QS + 1536 + h * 64 + d];
      g[qrow * D_ + h * 64 + d] = (__bf16)(o / (1.f + __expf(-o)) * uv);
    }
  }
}

extern "C" void kernel_launch(void* const* d_in, const int* in_sizes, int n_in,
                              void* d_out, int out_size, void* d_ws, size_t ws_size,
                              hipStream_t stream) {
  const float* x     = (const float*)d_in[0];
  const float* w_qkv = (const float*)d_in[1];
  const float* b_qkv = (const float*)d_in[2];
  const float* w_u   = (const float*)d_in[3];
  const float* b_u   = (const float*)d_in[4];
  const float* w_out = (const float*)d_in[5];
  const float* b_out = (const float*)d_in[6];
  float* out = (float*)d_out;

  char* ws = (char*)d_ws;
  __bf16* xb   = (__bf16*)ws;                           //  8 MB
  __bf16* wcat = (__bf16*)(ws + 8388608);               //  2 MB [w_qkv;w_u]
  __bf16* wob  = (__bf16*)(ws + 10485760);              //  0.5 MB
  float*  bcat = (float*) (ws + 11010048);              //  8 KB
  __bf16* qu   = (__bf16*)(ws + 11018240);              // 32 MB [q|k|v|u]
  __bf16* gb   = (__bf16*)(ws + 44572672);              //  8 MB

  // one-time opt-in for 128 KB dynamic LDS (host-side attr, graph-safe)
  static bool attr_done = []() {
    hipFuncSetAttribute((const void*)gemm256,
                        hipFuncAttributeMaxDynamicSharedMemorySize, 131072);
    return true;
  }();
  (void)attr_done;

  cvt_pack<<<dim3(2688), dim3(256), 0, stream>>>(
      x, w_qkv, w_u, w_out, b_qkv, b_u, xb, wcat, wob, bcat);
  gemm256<<<dim3(32, 8), dim3(512), 131072, stream>>>(
      xb, wcat, bcat, qu, 8192, 2048, 512);
  attn_tile<<<dim3(L_ / 128, H_, B_), dim3(512), 0, stream>>>(qu, gb);
  gemm_async<float><<<dim3(64, 4), dim3(256), 0, stream>>>(
      gb, wob, b_out, out, 8192, 512, 512);
}

// Round 6
// 143.072 us; speedup vs baseline: 2.9076x; 1.0334x over previous
//
#include <hip/hip_runtime.h>
#include <hip/hip_bf16.h>

typedef __bf16 bf16x8 __attribute__((ext_vector_type(8)));
typedef float f32x4 __attribute__((ext_vector_type(4)));

#define B_ 4
#define L_ 2048
#define D_ 512
#define H_ 8
#define QS 2048
#define SP 72

#define SB0 __builtin_amdgcn_sched_barrier(0)
#define WAIT_VM(n) asm volatile("s_waitcnt vmcnt(" #n ")" ::: "memory")
#define WAIT_LGKM0 asm volatile("s_waitcnt lgkmcnt(0)" ::: "memory")

// async 16B global -> LDS (gfx950 global_load_lds_dwordx4)
__device__ __forceinline__ void gl16(const __bf16* g, __bf16* l) {
  __builtin_amdgcn_global_load_lds(
      (const __attribute__((address_space(1))) void*)g,
      (__attribute__((address_space(3))) void*)l, 16, 0, 0);
}

// f32 -> bf16 conversion + packing. vec8 regions:
// x[0,524288) wqkv[524288,622592) wu[622592,655360) wout[655360,688128)
// Also builds bcat[2048] = [b_qkv ; b_u] (f32) in block 0.
__global__ __launch_bounds__(256) void cvt_pack(
    const float* __restrict__ x, const float* __restrict__ wq,
    const float* __restrict__ wu, const float* __restrict__ wo,
    const float* __restrict__ bq, const float* __restrict__ bu,
    __bf16* __restrict__ xb, __bf16* __restrict__ wcat,
    __bf16* __restrict__ wob, float* __restrict__ bcat)
{
  const int idx8 = blockIdx.x * 256 + threadIdx.x;
  const float* src; __bf16* dst; size_t so, dof;
  if (idx8 < 524288)      { src = x;  dst = xb;   so = (size_t)idx8 * 8;            dof = so; }
  else if (idx8 < 622592) { src = wq; dst = wcat; so = (size_t)(idx8 - 524288) * 8; dof = so; }
  else if (idx8 < 655360) { src = wu; dst = wcat; so = (size_t)(idx8 - 622592) * 8; dof = so + 786432; }
  else                    { src = wo; dst = wob;  so = (size_t)(idx8 - 655360) * 8; dof = so; }
  const float4 lo = *(const float4*)(src + so);
  const float4 hi = *(const float4*)(src + so + 4);
  bf16x8 r;
  r[0] = (__bf16)lo.x; r[1] = (__bf16)lo.y; r[2] = (__bf16)lo.z; r[3] = (__bf16)lo.w;
  r[4] = (__bf16)hi.x; r[5] = (__bf16)hi.y; r[6] = (__bf16)hi.z; r[7] = (__bf16)hi.w;
  *(bf16x8*)(dst + dof) = r;
  if (blockIdx.x == 0) {
#pragma unroll
    for (int e = 0; e < 8; ++e) {
      const int col = threadIdx.x * 8 + e;
      bcat[col] = (col < 1536) ? bq[col] : bu[col - 1536];
    }
  }
}

// ---------------------------------------------------------------------------
// 256x256 deep-pipelined GEMM (T2+T3+T4+T5), r2-green structure.
// ---------------------------------------------------------------------------
__global__ __launch_bounds__(512, 2) void gemm256(
    const __bf16* __restrict__ A, const __bf16* __restrict__ W,
    const float* __restrict__ bias, __bf16* __restrict__ C,
    int M, int N, int K)
{
  extern __shared__ char smem[];
  const int t = threadIdx.x;
  const int lane = t & 63;
  const int wave = t >> 6;
  const int wm = (wave >> 2) * 128;
  const int wn = (wave & 3) * 64;
  const int bm0 = blockIdx.x * 256;
  const int bn0 = blockIdx.y * 256;
  const int r = lane & 15, q = lane >> 4;
  const int nt = K >> 6;

  auto stage = [&](int kt, int p) {
#pragma unroll
    for (int j = 0; j < 4; ++j) {
      const int c = t + j * 512;
      const int row = c >> 3;
      const int cs = (c & 7) ^ (row & 7);
      gl16(A + (size_t)(bm0 + row) * K + kt * 64 + cs * 8,
           (__bf16*)(smem + p * 32768) + c * 8);
    }
#pragma unroll
    for (int j = 0; j < 4; ++j) {
      const int c = t + j * 512;
      const int row = c >> 3;
      const int cs = (c & 7) ^ (row & 7);
      gl16(W + (size_t)(bn0 + row) * K + kt * 64 + cs * 8,
           (__bf16*)(smem + 65536 + p * 32768) + c * 8);
    }
  };
  auto rdA = [&](int p, int mi, int ks) -> bf16x8 {
    const int row = wm + mi * 16 + r;
    const int byte = row * 128 + ((ks * 64 + q * 16) ^ ((row & 7) << 4));
    return *(const bf16x8*)(smem + p * 32768 + byte);
  };
  auto rdB = [&](int p, int ni, int ks) -> bf16x8 {
    const int row = wn + ni * 16 + r;
    const int byte = row * 128 + ((ks * 64 + q * 16) ^ ((row & 7) << 4));
    return *(const bf16x8*)(smem + 65536 + p * 32768 + byte);
  };

  f32x4 acc[8][4] = {};
  stage(0, 0);
  stage(1, 1);

  for (int kt = 0; kt < nt; ++kt) {
    const int p = kt & 1;
    if (kt < nt - 1) { WAIT_VM(8); } else { WAIT_VM(0); }
    SB0; __builtin_amdgcn_s_barrier(); SB0;

    bf16x8 a03[4][2], a47[4][2], b01[2][2], b23[2][2];
#pragma unroll
    for (int mi = 0; mi < 4; ++mi) { a03[mi][0] = rdA(p, mi, 0); a03[mi][1] = rdA(p, mi, 1); }
#pragma unroll
    for (int ni = 0; ni < 2; ++ni) { b01[ni][0] = rdB(p, ni, 0); b01[ni][1] = rdB(p, ni, 1); }
    __builtin_amdgcn_s_setprio(1);
#pragma unroll
    for (int mi = 0; mi < 4; ++mi)
#pragma unroll
      for (int ni = 0; ni < 2; ++ni) {
        acc[mi][ni] = __builtin_amdgcn_mfma_f32_16x16x32_bf16(a03[mi][0], b01[ni][0], acc[mi][ni], 0, 0, 0);
        acc[mi][ni] = __builtin_amdgcn_mfma_f32_16x16x32_bf16(a03[mi][1], b01[ni][1], acc[mi][ni], 0, 0, 0);
      }
    __builtin_amdgcn_s_setprio(0);
#pragma unroll
    for (int ni = 0; ni < 2; ++ni) { b23[ni][0] = rdB(p, ni + 2, 0); b23[ni][1] = rdB(p, ni + 2, 1); }
    __builtin_amdgcn_s_setprio(1);
#pragma unroll
    for (int mi = 0; mi < 4; ++mi)
#pragma unroll
      for (int ni = 0; ni < 2; ++ni) {
        acc[mi][ni + 2] = __builtin_amdgcn_mfma_f32_16x16x32_bf16(a03[mi][0], b23[ni][0], acc[mi][ni + 2], 0, 0, 0);
        acc[mi][ni + 2] = __builtin_amdgcn_mfma_f32_16x16x32_bf16(a03[mi][1], b23[ni][1], acc[mi][ni + 2], 0, 0, 0);
      }
    __builtin_amdgcn_s_setprio(0);
#pragma unroll
    for (int mi = 0; mi < 4; ++mi) { a47[mi][0] = rdA(p, mi + 4, 0); a47[mi][1] = rdA(p, mi + 4, 1); }
    __builtin_amdgcn_s_setprio(1);
#pragma unroll
    for (int mi = 0; mi < 4; ++mi)
#pragma unroll
      for (int ni = 0; ni < 2; ++ni) {
        acc[mi + 4][ni] = __builtin_amdgcn_mfma_f32_16x16x32_bf16(a47[mi][0], b01[ni][0], acc[mi + 4][ni], 0, 0, 0);
        acc[mi + 4][ni] = __builtin_amdgcn_mfma_f32_16x16x32_bf16(a47[mi][1], b01[ni][1], acc[mi + 4][ni], 0, 0, 0);
      }
    __builtin_amdgcn_s_setprio(0);
    WAIT_LGKM0;                 // all buf-p reads retired (WAR)
    SB0; __builtin_amdgcn_s_barrier(); SB0;
    if (kt + 2 < nt) stage(kt + 2, p);
    __builtin_amdgcn_s_setprio(1);
#pragma unroll
    for (int mi = 0; mi < 4; ++mi)
#pragma unroll
      for (int ni = 0; ni < 2; ++ni) {
        acc[mi + 4][ni + 2] = __builtin_amdgcn_mfma_f32_16x16x32_bf16(a47[mi][0], b23[ni][0], acc[mi + 4][ni + 2], 0, 0, 0);
        acc[mi + 4][ni + 2] = __builtin_amdgcn_mfma_f32_16x16x32_bf16(a47[mi][1], b23[ni][1], acc[mi + 4][ni + 2], 0, 0, 0);
      }
    __builtin_amdgcn_s_setprio(0);
  }

  const int cc = lane & 15, cq = lane >> 4;
#pragma unroll
  for (int mi = 0; mi < 8; ++mi) {
#pragma unroll
    for (int ni = 0; ni < 4; ++ni) {
      const int gcol = bn0 + wn + ni * 16 + cc;
      const float bv = bias[gcol];
#pragma unroll
      for (int rr = 0; rr < 4; ++rr) {
        const int grow = bm0 + wm + mi * 16 + cq * 4 + rr;
        C[(size_t)grow * N + gcol] = (__bf16)(acc[mi][ni][rr] + bv);
      }
    }
  }
}

// ---------------------------------------------------------------------------
// Out-proj GEMM: counted-vmcnt pipelined 64x128 tile, f32 out.
// out[8192][512] = gb[8192][512] @ wob[512][512]^T + bo.
// 256 thr = 4 waves (2M x 2N), per-wave 32x64 out (acc 2x4 f32x4 = 32 VGPR).
// LDS 48 KB (A 8K + B 16K, dbuf) -> grid 512 blocks = 2 blocks/CU: cross-
// block overlap hides the entry-barrier drains the m97 structure paid.
// Pipeline identical to gemm256: prologue 2 tiles, vmcnt(6) at entry
// (6 loads/tile, 12 in flight), stage kt+2 after the WAR barrier, T2
// swizzle both-sides, setprio around MFMA. Accumulation order k-ascending
// (same as the previous out-gemm) => bit-identical output.
// ---------------------------------------------------------------------------
__global__ __launch_bounds__(256, 2) void gemm_out(
    const __bf16* __restrict__ A, const __bf16* __restrict__ W,
    const float* __restrict__ bias, float* __restrict__ C)
{
  __shared__ char sm[49152];   // A: p*8192 (2x8K), B: 16384 + p*16384 (2x16K)
  const int t = threadIdx.x;
  const int lane = t & 63;
  const int wave = t >> 6;
  const int wm = (wave >> 1) * 32;
  const int wn = (wave & 1) * 64;
  const int bm0 = blockIdx.x * 64;
  const int bn0 = blockIdx.y * 128;
  const int r = lane & 15, q = lane >> 4;
  const int K = 512, N = 512;

  auto stage = [&](int kt, int p) {
#pragma unroll
    for (int j = 0; j < 2; ++j) {            // A: 512 chunks, 2/thread
      const int c = t + j * 256;
      const int row = c >> 3;
      const int cs = (c & 7) ^ (row & 7);
      gl16(A + (size_t)(bm0 + row) * K + kt * 64 + cs * 8,
           (__bf16*)(sm + p * 8192) + c * 8);
    }
#pragma unroll
    for (int j = 0; j < 4; ++j) {            // B: 1024 chunks, 4/thread
      const int c = t + j * 256;
      const int row = c >> 3;
      const int cs = (c & 7) ^ (row & 7);
      gl16(W + (size_t)(bn0 + row) * K + kt * 64 + cs * 8,
           (__bf16*)(sm + 16384 + p * 16384) + c * 8);
    }
  };
  auto rdA = [&](int p, int mi, int ks) -> bf16x8 {
    const int row = wm + mi * 16 + r;
    const int byte = row * 128 + ((ks * 64 + q * 16) ^ ((row & 7) << 4));
    return *(const bf16x8*)(sm + p * 8192 + byte);
  };
  auto rdB = [&](int p, int ni, int ks) -> bf16x8 {
    const int row = wn + ni * 16 + r;
    const int byte = row * 128 + ((ks * 64 + q * 16) ^ ((row & 7) << 4));
    return *(const bf16x8*)(sm + 16384 + p * 16384 + byte);
  };

  f32x4 acc[2][4] = {};
  stage(0, 0);
  stage(1, 1);

  for (int kt = 0; kt < 8; ++kt) {
    const int p = kt & 1;
    if (kt < 7) { WAIT_VM(6); } else { WAIT_VM(0); }
    SB0; __builtin_amdgcn_s_barrier(); SB0;

    bf16x8 a[2][2], b01[2][2], b23[2][2];
    // ph0: A + B01
#pragma unroll
    for (int mi = 0; mi < 2; ++mi) { a[mi][0] = rdA(p, mi, 0); a[mi][1] = rdA(p, mi, 1); }
#pragma unroll
    for (int ni = 0; ni < 2; ++ni) { b01[ni][0] = rdB(p, ni, 0); b01[ni][1] = rdB(p, ni, 1); }
    __builtin_amdgcn_s_setprio(1);
#pragma unroll
    for (int mi = 0; mi < 2; ++mi)
#pragma unroll
      for (int ni = 0; ni < 2; ++ni) {
        acc[mi][ni] = __builtin_amdgcn_mfma_f32_16x16x32_bf16(a[mi][0], b01[ni][0], acc[mi][ni], 0, 0, 0);
        acc[mi][ni] = __builtin_amdgcn_mfma_f32_16x16x32_bf16(a[mi][1], b01[ni][1], acc[mi][ni], 0, 0, 0);
      }
    __builtin_amdgcn_s_setprio(0);
    // ph1: B23 reads, then WAR barrier, then stage kt+2 overlapped with MFMA
#pragma unroll
    for (int ni = 0; ni < 2; ++ni) { b23[ni][0] = rdB(p, ni + 2, 0); b23[ni][1] = rdB(p, ni + 2, 1); }
    WAIT_LGKM0;                 // all buf-p reads retired
    SB0; __builtin_amdgcn_s_barrier(); SB0;
    if (kt + 2 < 8) stage(kt + 2, p);
    __builtin_amdgcn_s_setprio(1);
#pragma unroll
    for (int mi = 0; mi < 2; ++mi)
#pragma unroll
      for (int ni = 0; ni < 2; ++ni) {
        acc[mi][ni + 2] = __builtin_amdgcn_mfma_f32_16x16x32_bf16(a[mi][0], b23[ni][0], acc[mi][ni + 2], 0, 0, 0);
        acc[mi][ni + 2] = __builtin_amdgcn_mfma_f32_16x16x32_bf16(a[mi][1], b23[ni][1], acc[mi][ni + 2], 0, 0, 0);
      }
    __builtin_amdgcn_s_setprio(0);
  }

  const int cc = lane & 15, cq = lane >> 4;
#pragma unroll
  for (int mi = 0; mi < 2; ++mi) {
#pragma unroll
    for (int ni = 0; ni < 4; ++ni) {
      const int gcol = bn0 + wn + ni * 16 + cc;
      const float bv = bias[gcol];
#pragma unroll
      for (int rr = 0; rr < 4; ++rr) {
        const int grow = bm0 + wm + mi * 16 + cq * 4 + rr;
        C[(size_t)grow * N + gcol] = acc[mi][ni][rr] + bv;
      }
    }
  }
}

// Flash-style MFMA attention, QBLK=128 / 512 threads / 8 waves (r5 green).
__global__ __launch_bounds__(512) void attn_tile(
    const __bf16* __restrict__ qu,   // [B*L][2048]  q|k|v|u
    __bf16* __restrict__ g)          // [B*L][512]
{
  const int qt = blockIdx.x, h = blockIdx.y, b = blockIdx.z;
  const int t = threadIdx.x;
  const int lane = t & 63;
  const int w = t >> 6;                    // 8 waves, 16 q-rows each
  const int q0 = qt * 128, qmax = q0 + 127;
  const size_t bL = (size_t)b * L_;

  __shared__ __bf16 lK[4096];        // [64][64] bf16, XOR-swizzled rows (8KB)
  __shared__ __bf16 lV[64 * SP];     // V^T: [d 64][key 64] stride 72 (9KB)
  __shared__ __bf16 Pb[128 * SP];    // P: [q 128][key 64] stride 72 (18KB)

  const int cq = lane >> 4, cc = lane & 15;
  const int krow_st = t >> 3, kgb8 = t & 7;   // K-staging: 64 rows x 8 chunks

  bf16x8 aq0, aq1;
  {
    const __bf16* qsrc = qu + (bL + q0 + w * 16 + cc) * QS + h * 64 + cq * 8;
    aq0 = *(const bf16x8*)qsrc;
    aq1 = *(const bf16x8*)(qsrc + 32);
  }

  float mreg[4], lreg[4];
#pragma unroll
  for (int rr = 0; rr < 4; ++rr) { mreg[rr] = -1e30f; lreg[rr] = 0.f; }
  f32x4 acc_o[4] = {};

  int clist[8]; int ncl = 0;
  clist[ncl++] = 0;
  if (qmax >= 64) clist[ncl++] = 64;
  {
    int lo = 1984 - qmax; if (lo < 0) lo = 0; lo &= ~63;
    const int hik = min(qmax, 2048 - q0);
    for (int c = lo; c <= hik; c += 64)
      if (c >= 128) clist[ncl++] = c;
  }

  // prologue: tile-0 K/V into registers (T14 pipeline)
  bf16x8 k0r, var;
  {
    const __bf16* src = qu + (bL + clist[0] + krow_st) * QS + 512 + h * 64;
    k0r = *(const bf16x8*)(src + kgb8 * 8);
    const __bf16* vsrc = qu + (bL + clist[0] + lane) * QS + 1024 + h * 64 + w * 8;
    var = *(const bf16x8*)vsrc;
  }

  for (int ci = 0; ci < ncl; ++ci) {
    const int c0 = clist[ci];
    WAIT_VM(0);                                 // this tile's K/V landed
    SB0; __builtin_amdgcn_s_barrier(); SB0;     // WAR: prior tile's reads done
    {
      char* lkb = (char*)lK;
      const int sw = (krow_st & 7) << 4;
      *(bf16x8*)(lkb + ((krow_st * 128 + kgb8 * 16) ^ sw)) = k0r;
#pragma unroll
      for (int e = 0; e < 8; ++e)
        lV[(w * 8 + e) * SP + lane] = var[e];
    }
    if (ci + 1 < ncl) {                         // issue next tile's loads
      const int cn = clist[ci + 1];
      const __bf16* src = qu + (bL + cn + krow_st) * QS + 512 + h * 64;
      k0r = *(const bf16x8*)(src + kgb8 * 8);
      const __bf16* vsrc = qu + (bL + cn + lane) * QS + 1024 + h * 64 + w * 8;
      var = *(const bf16x8*)vsrc;
    }
    WAIT_LGKM0;                                 // my ds_writes retired
    SB0; __builtin_amdgcn_s_barrier(); SB0;     // RAW: all writes visible

    f32x4 s[4];
    {
      const char* lkb = (const char*)lK;
#pragma unroll
      for (int nt = 0; nt < 4; ++nt) {
        const int krow = nt * 16 + cc;
        const int sw = (krow & 7) << 4;
        bf16x8 bk0 = *(const bf16x8*)(lkb + ((krow * 128 + cq * 16) ^ sw));
        bf16x8 bk1 = *(const bf16x8*)(lkb + ((krow * 128 + 64 + cq * 16) ^ sw));
        f32x4 a = {};
        a = __builtin_amdgcn_mfma_f32_16x16x32_bf16(aq0, bk0, a, 0, 0, 0);
        a = __builtin_amdgcn_mfma_f32_16x16x32_bf16(aq1, bk1, a, 0, 0, 0);
        s[nt] = a;
      }
    }

#pragma unroll
    for (int nt = 0; nt < 4; ++nt) {
#pragma unroll
      for (int rr = 0; rr < 4; ++rr) {
        const int i = q0 + w * 16 + cq * 4 + rr;
        const int j = c0 + nt * 16 + cc;
        const int ij = i + j;
        const bool valid = (j <= i) &&
            ((ij >= 1984 && ij <= 2048) || (j <= 64 && ij <= 2048));
        s[nt][rr] = valid ? s[nt][rr] * 0.125f : -1e30f;
      }
    }

    f32x4 pm;
#pragma unroll
    for (int rr = 0; rr < 4; ++rr)
      pm[rr] = fmaxf(fmaxf(s[0][rr], s[1][rr]), fmaxf(s[2][rr], s[3][rr]));
#pragma unroll
    for (int m = 1; m < 16; m <<= 1) {
#pragma unroll
      for (int rr = 0; rr < 4; ++rr)
        pm[rr] = fmaxf(pm[rr], __shfl_xor(pm[rr], m, 64));
    }
    float corr[4];
#pragma unroll
    for (int rr = 0; rr < 4; ++rr) {
      const float nm = fmaxf(mreg[rr], pm[rr]);
      corr[rr] = __expf(mreg[rr] - nm);
      mreg[rr] = nm;
    }

    f32x4 ps = {};
#pragma unroll
    for (int nt = 0; nt < 4; ++nt) {
#pragma unroll
      for (int rr = 0; rr < 4; ++rr) {
        const float p = __expf(s[nt][rr] - mreg[rr]);
        ps[rr] += p;
        Pb[(w * 16 + cq * 4 + rr) * SP + nt * 16 + cc] = (__bf16)p;
      }
    }
#pragma unroll
    for (int m = 1; m < 16; m <<= 1) {
#pragma unroll
      for (int rr = 0; rr < 4; ++rr)
        ps[rr] += __shfl_xor(ps[rr], m, 64);
    }
#pragma unroll
    for (int rr = 0; rr < 4; ++rr) lreg[rr] = lreg[rr] * corr[rr] + ps[rr];

    {
      bf16x8 pa0 = *(const bf16x8*)(Pb + (w * 16 + cc) * SP + cq * 8);
      bf16x8 pa1 = *(const bf16x8*)(Pb + (w * 16 + cc) * SP + 32 + cq * 8);
#pragma unroll
      for (int dt = 0; dt < 4; ++dt) {
#pragma unroll
        for (int rr = 0; rr < 4; ++rr) acc_o[dt][rr] *= corr[rr];
        bf16x8 vb0 = *(const bf16x8*)(lV + (dt * 16 + cc) * SP + cq * 8);
        bf16x8 vb1 = *(const bf16x8*)(lV + (dt * 16 + cc) * SP + 32 + cq * 8);
        acc_o[dt] = __builtin_amdgcn_mfma_f32_16x16x32_bf16(pa0, vb0, acc_o[dt], 0, 0, 0);
        acc_o[dt] = __builtin_amdgcn_mfma_f32_16x16x32_bf16(pa1, vb1, acc_o[dt], 0, 0, 0);
      }
    }
  }

  // epilogue: register state only
#pragma unroll
  for (int dt = 0; dt < 4; ++dt) {
#pragma unroll
    for (int rr = 0; rr < 4; ++rr) {
      const int row16 = cq * 4 + rr;
      const size_t qrow = bL + q0 + w * 16 + row16;
      const int d = dt * 16 + cc;
      const float o = acc_o[dt][rr] / fmaxf(lreg[rr], 1e-30f);
      const float uv = (float)qu[qrow * QS + 1536 + h * 64 + d];
      g[qrow * D_ + h * 64 + d] = (__bf16)(o / (1.f + __expf(-o)) * uv);
    }
  }
}

extern "C" void kernel_launch(void* const* d_in, const int* in_sizes, int n_in,
                              void* d_out, int out_size, void* d_ws, size_t ws_size,
                              hipStream_t stream) {
  const float* x     = (const float*)d_in[0];
  const float* w_qkv = (const float*)d_in[1];
  const float* b_qkv = (const float*)d_in[2];
  const float* w_u   = (const float*)d_in[3];
  const float* b_u   = (const float*)d_in[4];
  const float* w_out = (const float*)d_in[5];
  const float* b_out = (const float*)d_in[6];
  float* out = (float*)d_out;

  char* ws = (char*)d_ws;
  __bf16* xb   = (__bf16*)ws;                           //  8 MB
  __bf16* wcat = (__bf16*)(ws + 8388608);               //  2 MB [w_qkv;w_u]
  __bf16* wob  = (__bf16*)(ws + 10485760);              //  0.5 MB
  float*  bcat = (float*) (ws + 11010048);              //  8 KB
  __bf16* qu   = (__bf16*)(ws + 11018240);              // 32 MB [q|k|v|u]
  __bf16* gb   = (__bf16*)(ws + 44572672);              //  8 MB

  // one-time opt-in for 128 KB dynamic LDS (host-side attr, graph-safe)
  static bool attr_done = []() {
    hipFuncSetAttribute((const void*)gemm256,
                        hipFuncAttributeMaxDynamicSharedMemorySize, 131072);
    return true;
  }();
  (void)attr_done;

  cvt_pack<<<dim3(2688), dim3(256), 0, stream>>>(
      x, w_qkv, w_u, w_out, b_qkv, b_u, xb, wcat, wob, bcat);
  gemm256<<<dim3(32, 8), dim3(512), 131072, stream>>>(
      xb, wcat, bcat, qu, 8192, 2048, 512);
  attn_tile<<<dim3(L_ / 128, H_, B_), dim3(512), 0, stream>>>(qu, gb);
  gemm_out<<<dim3(128, 4), dim3(256), 0, stream>>>(
      gb, wob, b_out, out);
}

// Round 7
// 139.003 us; speedup vs baseline: 2.9927x; 1.0293x over previous
//
#include <hip/hip_runtime.h>
#include <hip/hip_bf16.h>

typedef __bf16 bf16x8 __attribute__((ext_vector_type(8)));
typedef float f32x4 __attribute__((ext_vector_type(4)));

#define B_ 4
#define L_ 2048
#define D_ 512
#define H_ 8
#define QS 2048
#define SP 72

#define SB0 __builtin_amdgcn_sched_barrier(0)
#define WAIT_VM(n) asm volatile("s_waitcnt vmcnt(" #n ")" ::: "memory")
#define WAIT_LGKM0 asm volatile("s_waitcnt lgkmcnt(0)" ::: "memory")

// async 16B global -> LDS (gfx950 global_load_lds_dwordx4)
__device__ __forceinline__ void gl16(const __bf16* g, __bf16* l) {
  __builtin_amdgcn_global_load_lds(
      (const __attribute__((address_space(1))) void*)g,
      (__attribute__((address_space(3))) void*)l, 16, 0, 0);
}

// f32 -> bf16 conversion + packing. vec8 regions:
// x[0,524288) wqkv[524288,622592) wu[622592,655360) wout[655360,688128)
// Also builds bcat[2048] = [b_qkv ; b_u] (f32) in block 0.
__global__ __launch_bounds__(256) void cvt_pack(
    const float* __restrict__ x, const float* __restrict__ wq,
    const float* __restrict__ wu, const float* __restrict__ wo,
    const float* __restrict__ bq, const float* __restrict__ bu,
    __bf16* __restrict__ xb, __bf16* __restrict__ wcat,
    __bf16* __restrict__ wob, float* __restrict__ bcat)
{
  const int idx8 = blockIdx.x * 256 + threadIdx.x;
  const float* src; __bf16* dst; size_t so, dof;
  if (idx8 < 524288)      { src = x;  dst = xb;   so = (size_t)idx8 * 8;            dof = so; }
  else if (idx8 < 622592) { src = wq; dst = wcat; so = (size_t)(idx8 - 524288) * 8; dof = so; }
  else if (idx8 < 655360) { src = wu; dst = wcat; so = (size_t)(idx8 - 622592) * 8; dof = so + 786432; }
  else                    { src = wo; dst = wob;  so = (size_t)(idx8 - 655360) * 8; dof = so; }
  const float4 lo = *(const float4*)(src + so);
  const float4 hi = *(const float4*)(src + so + 4);
  bf16x8 r;
  r[0] = (__bf16)lo.x; r[1] = (__bf16)lo.y; r[2] = (__bf16)lo.z; r[3] = (__bf16)lo.w;
  r[4] = (__bf16)hi.x; r[5] = (__bf16)hi.y; r[6] = (__bf16)hi.z; r[7] = (__bf16)hi.w;
  *(bf16x8*)(dst + dof) = r;
  if (blockIdx.x == 0) {
#pragma unroll
    for (int e = 0; e < 8; ++e) {
      const int col = threadIdx.x * 8 + e;
      bcat[col] = (col < 1536) ? bq[col] : bu[col - 1536];
    }
  }
}

// ---------------------------------------------------------------------------
// 256x256 deep-pipelined GEMM (T2+T3+T4+T5), r2-green structure, with the
// LAST K-tile peeled: each output quadrant's stores issue right after its
// final MFMA cluster, overlapping the remaining quadrants' ds_reads+MFMA.
// Mechanism: grid = 256 blocks = 1/CU (single scheduling wave) => without the
// peel, the entire 32 MB C-write burst (~5 us HBM) overlaps with nothing.
// Values/order/addresses identical; only store issue-order changes.
// ---------------------------------------------------------------------------
__global__ __launch_bounds__(512, 2) void gemm256(
    const __bf16* __restrict__ A, const __bf16* __restrict__ W,
    const float* __restrict__ bias, __bf16* __restrict__ C,
    int M, int N, int K)
{
  extern __shared__ char smem[];
  const int t = threadIdx.x;
  const int lane = t & 63;
  const int wave = t >> 6;
  const int wm = (wave >> 2) * 128;
  const int wn = (wave & 3) * 64;
  const int bm0 = blockIdx.x * 256;
  const int bn0 = blockIdx.y * 256;
  const int r = lane & 15, q = lane >> 4;
  const int nt = K >> 6;

  auto stage = [&](int kt, int p) {
#pragma unroll
    for (int j = 0; j < 4; ++j) {
      const int c = t + j * 512;
      const int row = c >> 3;
      const int cs = (c & 7) ^ (row & 7);
      gl16(A + (size_t)(bm0 + row) * K + kt * 64 + cs * 8,
           (__bf16*)(smem + p * 32768) + c * 8);
    }
#pragma unroll
    for (int j = 0; j < 4; ++j) {
      const int c = t + j * 512;
      const int row = c >> 3;
      const int cs = (c & 7) ^ (row & 7);
      gl16(W + (size_t)(bn0 + row) * K + kt * 64 + cs * 8,
           (__bf16*)(smem + 65536 + p * 32768) + c * 8);
    }
  };
  auto rdA = [&](int p, int mi, int ks) -> bf16x8 {
    const int row = wm + mi * 16 + r;
    const int byte = row * 128 + ((ks * 64 + q * 16) ^ ((row & 7) << 4));
    return *(const bf16x8*)(smem + p * 32768 + byte);
  };
  auto rdB = [&](int p, int ni, int ks) -> bf16x8 {
    const int row = wn + ni * 16 + r;
    const int byte = row * 128 + ((ks * 64 + q * 16) ^ ((row & 7) << 4));
    return *(const bf16x8*)(smem + 65536 + p * 32768 + byte);
  };

  f32x4 acc[8][4] = {};
  stage(0, 0);
  stage(1, 1);

  for (int kt = 0; kt < nt - 1; ++kt) {
    const int p = kt & 1;
    WAIT_VM(8);
    SB0; __builtin_amdgcn_s_barrier(); SB0;

    bf16x8 a03[4][2], a47[4][2], b01[2][2], b23[2][2];
#pragma unroll
    for (int mi = 0; mi < 4; ++mi) { a03[mi][0] = rdA(p, mi, 0); a03[mi][1] = rdA(p, mi, 1); }
#pragma unroll
    for (int ni = 0; ni < 2; ++ni) { b01[ni][0] = rdB(p, ni, 0); b01[ni][1] = rdB(p, ni, 1); }
    __builtin_amdgcn_s_setprio(1);
#pragma unroll
    for (int mi = 0; mi < 4; ++mi)
#pragma unroll
      for (int ni = 0; ni < 2; ++ni) {
        acc[mi][ni] = __builtin_amdgcn_mfma_f32_16x16x32_bf16(a03[mi][0], b01[ni][0], acc[mi][ni], 0, 0, 0);
        acc[mi][ni] = __builtin_amdgcn_mfma_f32_16x16x32_bf16(a03[mi][1], b01[ni][1], acc[mi][ni], 0, 0, 0);
      }
    __builtin_amdgcn_s_setprio(0);
#pragma unroll
    for (int ni = 0; ni < 2; ++ni) { b23[ni][0] = rdB(p, ni + 2, 0); b23[ni][1] = rdB(p, ni + 2, 1); }
    __builtin_amdgcn_s_setprio(1);
#pragma unroll
    for (int mi = 0; mi < 4; ++mi)
#pragma unroll
      for (int ni = 0; ni < 2; ++ni) {
        acc[mi][ni + 2] = __builtin_amdgcn_mfma_f32_16x16x32_bf16(a03[mi][0], b23[ni][0], acc[mi][ni + 2], 0, 0, 0);
        acc[mi][ni + 2] = __builtin_amdgcn_mfma_f32_16x16x32_bf16(a03[mi][1], b23[ni][1], acc[mi][ni + 2], 0, 0, 0);
      }
    __builtin_amdgcn_s_setprio(0);
#pragma unroll
    for (int mi = 0; mi < 4; ++mi) { a47[mi][0] = rdA(p, mi + 4, 0); a47[mi][1] = rdA(p, mi + 4, 1); }
    __builtin_amdgcn_s_setprio(1);
#pragma unroll
    for (int mi = 0; mi < 4; ++mi)
#pragma unroll
      for (int ni = 0; ni < 2; ++ni) {
        acc[mi + 4][ni] = __builtin_amdgcn_mfma_f32_16x16x32_bf16(a47[mi][0], b01[ni][0], acc[mi + 4][ni], 0, 0, 0);
        acc[mi + 4][ni] = __builtin_amdgcn_mfma_f32_16x16x32_bf16(a47[mi][1], b01[ni][1], acc[mi + 4][ni], 0, 0, 0);
      }
    __builtin_amdgcn_s_setprio(0);
    WAIT_LGKM0;                 // all buf-p reads retired (WAR)
    SB0; __builtin_amdgcn_s_barrier(); SB0;
    if (kt + 2 < nt) stage(kt + 2, p);
    __builtin_amdgcn_s_setprio(1);
#pragma unroll
    for (int mi = 0; mi < 4; ++mi)
#pragma unroll
      for (int ni = 0; ni < 2; ++ni) {
        acc[mi + 4][ni + 2] = __builtin_amdgcn_mfma_f32_16x16x32_bf16(a47[mi][0], b23[ni][0], acc[mi + 4][ni + 2], 0, 0, 0);
        acc[mi + 4][ni + 2] = __builtin_amdgcn_mfma_f32_16x16x32_bf16(a47[mi][1], b23[ni][1], acc[mi + 4][ni + 2], 0, 0, 0);
      }
    __builtin_amdgcn_s_setprio(0);
  }

  // ---- peeled last tile: interleave C-stores with remaining compute ----
  {
    const int p = (nt - 1) & 1;
    const int cc = lane & 15, cq = lane >> 4;
    WAIT_VM(0);
    SB0; __builtin_amdgcn_s_barrier(); SB0;

    float bv[4];
#pragma unroll
    for (int ni = 0; ni < 4; ++ni) bv[ni] = bias[bn0 + wn + ni * 16 + cc];

    auto st = [&](int mi, int ni) {
      const int gcol = bn0 + wn + ni * 16 + cc;
#pragma unroll
      for (int rr = 0; rr < 4; ++rr) {
        const int grow = bm0 + wm + mi * 16 + cq * 4 + rr;
        C[(size_t)grow * N + gcol] = (__bf16)(acc[mi][ni][rr] + bv[ni]);
      }
    };

    bf16x8 a03[4][2], a47[4][2], b01[2][2], b23[2][2];
#pragma unroll
    for (int mi = 0; mi < 4; ++mi) { a03[mi][0] = rdA(p, mi, 0); a03[mi][1] = rdA(p, mi, 1); }
#pragma unroll
    for (int ni = 0; ni < 2; ++ni) { b01[ni][0] = rdB(p, ni, 0); b01[ni][1] = rdB(p, ni, 1); }
    __builtin_amdgcn_s_setprio(1);
#pragma unroll
    for (int mi = 0; mi < 4; ++mi)
#pragma unroll
      for (int ni = 0; ni < 2; ++ni) {
        acc[mi][ni] = __builtin_amdgcn_mfma_f32_16x16x32_bf16(a03[mi][0], b01[ni][0], acc[mi][ni], 0, 0, 0);
        acc[mi][ni] = __builtin_amdgcn_mfma_f32_16x16x32_bf16(a03[mi][1], b01[ni][1], acc[mi][ni], 0, 0, 0);
      }
    __builtin_amdgcn_s_setprio(0);
#pragma unroll
    for (int mi = 0; mi < 4; ++mi)
#pragma unroll
      for (int ni = 0; ni < 2; ++ni) st(mi, ni);          // quadrant 0 out

#pragma unroll
    for (int ni = 0; ni < 2; ++ni) { b23[ni][0] = rdB(p, ni + 2, 0); b23[ni][1] = rdB(p, ni + 2, 1); }
    __builtin_amdgcn_s_setprio(1);
#pragma unroll
    for (int mi = 0; mi < 4; ++mi)
#pragma unroll
      for (int ni = 0; ni < 2; ++ni) {
        acc[mi][ni + 2] = __builtin_amdgcn_mfma_f32_16x16x32_bf16(a03[mi][0], b23[ni][0], acc[mi][ni + 2], 0, 0, 0);
        acc[mi][ni + 2] = __builtin_amdgcn_mfma_f32_16x16x32_bf16(a03[mi][1], b23[ni][1], acc[mi][ni + 2], 0, 0, 0);
      }
    __builtin_amdgcn_s_setprio(0);
#pragma unroll
    for (int mi = 0; mi < 4; ++mi)
#pragma unroll
      for (int ni = 2; ni < 4; ++ni) st(mi, ni);          // quadrant 1 out

#pragma unroll
    for (int mi = 0; mi < 4; ++mi) { a47[mi][0] = rdA(p, mi + 4, 0); a47[mi][1] = rdA(p, mi + 4, 1); }
    __builtin_amdgcn_s_setprio(1);
#pragma unroll
    for (int mi = 0; mi < 4; ++mi)
#pragma unroll
      for (int ni = 0; ni < 2; ++ni) {
        acc[mi + 4][ni] = __builtin_amdgcn_mfma_f32_16x16x32_bf16(a47[mi][0], b01[ni][0], acc[mi + 4][ni], 0, 0, 0);
        acc[mi + 4][ni] = __builtin_amdgcn_mfma_f32_16x16x32_bf16(a47[mi][1], b01[ni][1], acc[mi + 4][ni], 0, 0, 0);
      }
    __builtin_amdgcn_s_setprio(0);
#pragma unroll
    for (int mi = 4; mi < 8; ++mi)
#pragma unroll
      for (int ni = 0; ni < 2; ++ni) st(mi, ni);          // quadrant 2 out

    __builtin_amdgcn_s_setprio(1);
#pragma unroll
    for (int mi = 0; mi < 4; ++mi)
#pragma unroll
      for (int ni = 0; ni < 2; ++ni) {
        acc[mi + 4][ni + 2] = __builtin_amdgcn_mfma_f32_16x16x32_bf16(a47[mi][0], b23[ni][0], acc[mi + 4][ni + 2], 0, 0, 0);
        acc[mi + 4][ni + 2] = __builtin_amdgcn_mfma_f32_16x16x32_bf16(a47[mi][1], b23[ni][1], acc[mi + 4][ni + 2], 0, 0, 0);
      }
    __builtin_amdgcn_s_setprio(0);
#pragma unroll
    for (int mi = 4; mi < 8; ++mi)
#pragma unroll
      for (int ni = 2; ni < 4; ++ni) st(mi, ni);          // quadrant 3 out
  }
}

// ---------------------------------------------------------------------------
// Out-proj GEMM: counted-vmcnt pipelined 64x128 tile, f32 out (r6 green),
// with the same last-tile store interleave.
// ---------------------------------------------------------------------------
__global__ __launch_bounds__(256, 2) void gemm_out(
    const __bf16* __restrict__ A, const __bf16* __restrict__ W,
    const float* __restrict__ bias, float* __restrict__ C)
{
  __shared__ char sm[49152];   // A: p*8192 (2x8K), B: 16384 + p*16384 (2x16K)
  const int t = threadIdx.x;
  const int lane = t & 63;
  const int wave = t >> 6;
  const int wm = (wave >> 1) * 32;
  const int wn = (wave & 1) * 64;
  const int bm0 = blockIdx.x * 64;
  const int bn0 = blockIdx.y * 128;
  const int r = lane & 15, q = lane >> 4;
  const int K = 512, N = 512;

  auto stage = [&](int kt, int p) {
#pragma unroll
    for (int j = 0; j < 2; ++j) {            // A: 512 chunks, 2/thread
      const int c = t + j * 256;
      const int row = c >> 3;
      const int cs = (c & 7) ^ (row & 7);
      gl16(A + (size_t)(bm0 + row) * K + kt * 64 + cs * 8,
           (__bf16*)(sm + p * 8192) + c * 8);
    }
#pragma unroll
    for (int j = 0; j < 4; ++j) {            // B: 1024 chunks, 4/thread
      const int c = t + j * 256;
      const int row = c >> 3;
      const int cs = (c & 7) ^ (row & 7);
      gl16(W + (size_t)(bn0 + row) * K + kt * 64 + cs * 8,
           (__bf16*)(sm + 16384 + p * 16384) + c * 8);
    }
  };
  auto rdA = [&](int p, int mi, int ks) -> bf16x8 {
    const int row = wm + mi * 16 + r;
    const int byte = row * 128 + ((ks * 64 + q * 16) ^ ((row & 7) << 4));
    return *(const bf16x8*)(sm + p * 8192 + byte);
  };
  auto rdB = [&](int p, int ni, int ks) -> bf16x8 {
    const int row = wn + ni * 16 + r;
    const int byte = row * 128 + ((ks * 64 + q * 16) ^ ((row & 7) << 4));
    return *(const bf16x8*)(sm + 16384 + p * 16384 + byte);
  };

  f32x4 acc[2][4] = {};
  stage(0, 0);
  stage(1, 1);

  for (int kt = 0; kt < 7; ++kt) {
    const int p = kt & 1;
    WAIT_VM(6);
    SB0; __builtin_amdgcn_s_barrier(); SB0;

    bf16x8 a[2][2], b01[2][2], b23[2][2];
#pragma unroll
    for (int mi = 0; mi < 2; ++mi) { a[mi][0] = rdA(p, mi, 0); a[mi][1] = rdA(p, mi, 1); }
#pragma unroll
    for (int ni = 0; ni < 2; ++ni) { b01[ni][0] = rdB(p, ni, 0); b01[ni][1] = rdB(p, ni, 1); }
    __builtin_amdgcn_s_setprio(1);
#pragma unroll
    for (int mi = 0; mi < 2; ++mi)
#pragma unroll
      for (int ni = 0; ni < 2; ++ni) {
        acc[mi][ni] = __builtin_amdgcn_mfma_f32_16x16x32_bf16(a[mi][0], b01[ni][0], acc[mi][ni], 0, 0, 0);
        acc[mi][ni] = __builtin_amdgcn_mfma_f32_16x16x32_bf16(a[mi][1], b01[ni][1], acc[mi][ni], 0, 0, 0);
      }
    __builtin_amdgcn_s_setprio(0);
#pragma unroll
    for (int ni = 0; ni < 2; ++ni) { b23[ni][0] = rdB(p, ni + 2, 0); b23[ni][1] = rdB(p, ni + 2, 1); }
    WAIT_LGKM0;                 // all buf-p reads retired
    SB0; __builtin_amdgcn_s_barrier(); SB0;
    if (kt + 2 < 8) stage(kt + 2, p);
    __builtin_amdgcn_s_setprio(1);
#pragma unroll
    for (int mi = 0; mi < 2; ++mi)
#pragma unroll
      for (int ni = 0; ni < 2; ++ni) {
        acc[mi][ni + 2] = __builtin_amdgcn_mfma_f32_16x16x32_bf16(a[mi][0], b23[ni][0], acc[mi][ni + 2], 0, 0, 0);
        acc[mi][ni + 2] = __builtin_amdgcn_mfma_f32_16x16x32_bf16(a[mi][1], b23[ni][1], acc[mi][ni + 2], 0, 0, 0);
      }
    __builtin_amdgcn_s_setprio(0);
  }

  // ---- peeled last tile (kt=7, p=1): stores interleaved ----
  {
    const int p = 1;
    const int cc = lane & 15, cq = lane >> 4;
    WAIT_VM(0);
    SB0; __builtin_amdgcn_s_barrier(); SB0;

    float bv[4];
#pragma unroll
    for (int ni = 0; ni < 4; ++ni) bv[ni] = bias[bn0 + wn + ni * 16 + cc];

    auto st = [&](int mi, int ni) {
      const int gcol = bn0 + wn + ni * 16 + cc;
#pragma unroll
      for (int rr = 0; rr < 4; ++rr) {
        const int grow = bm0 + wm + mi * 16 + cq * 4 + rr;
        C[(size_t)grow * N + gcol] = acc[mi][ni][rr] + bv[ni];
      }
    };

    bf16x8 a[2][2], b01[2][2], b23[2][2];
#pragma unroll
    for (int mi = 0; mi < 2; ++mi) { a[mi][0] = rdA(p, mi, 0); a[mi][1] = rdA(p, mi, 1); }
#pragma unroll
    for (int ni = 0; ni < 2; ++ni) { b01[ni][0] = rdB(p, ni, 0); b01[ni][1] = rdB(p, ni, 1); }
    __builtin_amdgcn_s_setprio(1);
#pragma unroll
    for (int mi = 0; mi < 2; ++mi)
#pragma unroll
      for (int ni = 0; ni < 2; ++ni) {
        acc[mi][ni] = __builtin_amdgcn_mfma_f32_16x16x32_bf16(a[mi][0], b01[ni][0], acc[mi][ni], 0, 0, 0);
        acc[mi][ni] = __builtin_amdgcn_mfma_f32_16x16x32_bf16(a[mi][1], b01[ni][1], acc[mi][ni], 0, 0, 0);
      }
    __builtin_amdgcn_s_setprio(0);
#pragma unroll
    for (int mi = 0; mi < 2; ++mi)
#pragma unroll
      for (int ni = 0; ni < 2; ++ni) st(mi, ni);          // half 0 out

#pragma unroll
    for (int ni = 0; ni < 2; ++ni) { b23[ni][0] = rdB(p, ni + 2, 0); b23[ni][1] = rdB(p, ni + 2, 1); }
    __builtin_amdgcn_s_setprio(1);
#pragma unroll
    for (int mi = 0; mi < 2; ++mi)
#pragma unroll
      for (int ni = 0; ni < 2; ++ni) {
        acc[mi][ni + 2] = __builtin_amdgcn_mfma_f32_16x16x32_bf16(a[mi][0], b23[ni][0], acc[mi][ni + 2], 0, 0, 0);
        acc[mi][ni + 2] = __builtin_amdgcn_mfma_f32_16x16x32_bf16(a[mi][1], b23[ni][1], acc[mi][ni + 2], 0, 0, 0);
      }
    __builtin_amdgcn_s_setprio(0);
#pragma unroll
    for (int mi = 0; mi < 2; ++mi)
#pragma unroll
      for (int ni = 2; ni < 4; ++ni) st(mi, ni);          // half 1 out
  }
}

// Flash-style MFMA attention, QBLK=128 / 512 threads / 8 waves (r5 green).
__global__ __launch_bounds__(512) void attn_tile(
    const __bf16* __restrict__ qu,   // [B*L][2048]  q|k|v|u
    __bf16* __restrict__ g)          // [B*L][512]
{
  const int qt = blockIdx.x, h = blockIdx.y, b = blockIdx.z;
  const int t = threadIdx.x;
  const int lane = t & 63;
  const int w = t >> 6;                    // 8 waves, 16 q-rows each
  const int q0 = qt * 128, qmax = q0 + 127;
  const size_t bL = (size_t)b * L_;

  __shared__ __bf16 lK[4096];        // [64][64] bf16, XOR-swizzled rows (8KB)
  __shared__ __bf16 lV[64 * SP];     // V^T: [d 64][key 64] stride 72 (9KB)
  __shared__ __bf16 Pb[128 * SP];    // P: [q 128][key 64] stride 72 (18KB)

  const int cq = lane >> 4, cc = lane & 15;
  const int krow_st = t >> 3, kgb8 = t & 7;   // K-staging: 64 rows x 8 chunks

  bf16x8 aq0, aq1;
  {
    const __bf16* qsrc = qu + (bL + q0 + w * 16 + cc) * QS + h * 64 + cq * 8;
    aq0 = *(const bf16x8*)qsrc;
    aq1 = *(const bf16x8*)(qsrc + 32);
  }

  float mreg[4], lreg[4];
#pragma unroll
  for (int rr = 0; rr < 4; ++rr) { mreg[rr] = -1e30f; lreg[rr] = 0.f; }
  f32x4 acc_o[4] = {};

  int clist[8]; int ncl = 0;
  clist[ncl++] = 0;
  if (qmax >= 64) clist[ncl++] = 64;
  {
    int lo = 1984 - qmax; if (lo < 0) lo = 0; lo &= ~63;
    const int hik = min(qmax, 2048 - q0);
    for (int c = lo; c <= hik; c += 64)
      if (c >= 128) clist[ncl++] = c;
  }

  // prologue: tile-0 K/V into registers (T14 pipeline)
  bf16x8 k0r, var;
  {
    const __bf16* src = qu + (bL + clist[0] + krow_st) * QS + 512 + h * 64;
    k0r = *(const bf16x8*)(src + kgb8 * 8);
    const __bf16* vsrc = qu + (bL + clist[0] + lane) * QS + 1024 + h * 64 + w * 8;
    var = *(const bf16x8*)vsrc;
  }

  for (int ci = 0; ci < ncl; ++ci) {
    const int c0 = clist[ci];
    WAIT_VM(0);                                 // this tile's K/V landed
    SB0; __builtin_amdgcn_s_barrier(); SB0;     // WAR: prior tile's reads done
    {
      char* lkb = (char*)lK;
      const int sw = (krow_st & 7) << 4;
      *(bf16x8*)(lkb + ((krow_st * 128 + kgb8 * 16) ^ sw)) = k0r;
#pragma unroll
      for (int e = 0; e < 8; ++e)
        lV[(w * 8 + e) * SP + lane] = var[e];
    }
    if (ci + 1 < ncl) {                         // issue next tile's loads
      const int cn = clist[ci + 1];
      const __bf16* src = qu + (bL + cn + krow_st) * QS + 512 + h * 64;
      k0r = *(const bf16x8*)(src + kgb8 * 8);
      const __bf16* vsrc = qu + (bL + cn + lane) * QS + 1024 + h * 64 + w * 8;
      var = *(const bf16x8*)vsrc;
    }
    WAIT_LGKM0;                                 // my ds_writes retired
    SB0; __builtin_amdgcn_s_barrier(); SB0;     // RAW: all writes visible

    f32x4 s[4];
    {
      const char* lkb = (const char*)lK;
#pragma unroll
      for (int nt = 0; nt < 4; ++nt) {
        const int krow = nt * 16 + cc;
        const int sw = (krow & 7) << 4;
        bf16x8 bk0 = *(const bf16x8*)(lkb + ((krow * 128 + cq * 16) ^ sw));
        bf16x8 bk1 = *(const bf16x8*)(lkb + ((krow * 128 + 64 + cq * 16) ^ sw));
        f32x4 a = {};
        a = __builtin_amdgcn_mfma_f32_16x16x32_bf16(aq0, bk0, a, 0, 0, 0);
        a = __builtin_amdgcn_mfma_f32_16x16x32_bf16(aq1, bk1, a, 0, 0, 0);
        s[nt] = a;
      }
    }

#pragma unroll
    for (int nt = 0; nt < 4; ++nt) {
#pragma unroll
      for (int rr = 0; rr < 4; ++rr) {
        const int i = q0 + w * 16 + cq * 4 + rr;
        const int j = c0 + nt * 16 + cc;
        const int ij = i + j;
        const bool valid = (j <= i) &&
            ((ij >= 1984 && ij <= 2048) || (j <= 64 && ij <= 2048));
        s[nt][rr] = valid ? s[nt][rr] * 0.125f : -1e30f;
      }
    }

    f32x4 pm;
#pragma unroll
    for (int rr = 0; rr < 4; ++rr)
      pm[rr] = fmaxf(fmaxf(s[0][rr], s[1][rr]), fmaxf(s[2][rr], s[3][rr]));
#pragma unroll
    for (int m = 1; m < 16; m <<= 1) {
#pragma unroll
      for (int rr = 0; rr < 4; ++rr)
        pm[rr] = fmaxf(pm[rr], __shfl_xor(pm[rr], m, 64));
    }
    float corr[4];
#pragma unroll
    for (int rr = 0; rr < 4; ++rr) {
      const float nm = fmaxf(mreg[rr], pm[rr]);
      corr[rr] = __expf(mreg[rr] - nm);
      mreg[rr] = nm;
    }

    f32x4 ps = {};
#pragma unroll
    for (int nt = 0; nt < 4; ++nt) {
#pragma unroll
      for (int rr = 0; rr < 4; ++rr) {
        const float p = __expf(s[nt][rr] - mreg[rr]);
        ps[rr] += p;
        Pb[(w * 16 + cq * 4 + rr) * SP + nt * 16 + cc] = (__bf16)p;
      }
    }
#pragma unroll
    for (int m = 1; m < 16; m <<= 1) {
#pragma unroll
      for (int rr = 0; rr < 4; ++rr)
        ps[rr] += __shfl_xor(ps[rr], m, 64);
    }
#pragma unroll
    for (int rr = 0; rr < 4; ++rr) lreg[rr] = lreg[rr] * corr[rr] + ps[rr];

    {
      bf16x8 pa0 = *(const bf16x8*)(Pb + (w * 16 + cc) * SP + cq * 8);
      bf16x8 pa1 = *(const bf16x8*)(Pb + (w * 16 + cc) * SP + 32 + cq * 8);
#pragma unroll
      for (int dt = 0; dt < 4; ++dt) {
#pragma unroll
        for (int rr = 0; rr < 4; ++rr) acc_o[dt][rr] *= corr[rr];
        bf16x8 vb0 = *(const bf16x8*)(lV + (dt * 16 + cc) * SP + cq * 8);
        bf16x8 vb1 = *(const bf16x8*)(lV + (dt * 16 + cc) * SP + 32 + cq * 8);
        acc_o[dt] = __builtin_amdgcn_mfma_f32_16x16x32_bf16(pa0, vb0, acc_o[dt], 0, 0, 0);
        acc_o[dt] = __builtin_amdgcn_mfma_f32_16x16x32_bf16(pa1, vb1, acc_o[dt], 0, 0, 0);
      }
    }
  }

  // epilogue: register state only
#pragma unroll
  for (int dt = 0; dt < 4; ++dt) {
#pragma unroll
    for (int rr = 0; rr < 4; ++rr) {
      const int row16 = cq * 4 + rr;
      const size_t qrow = bL + q0 + w * 16 + row16;
      const int d = dt * 16 + cc;
      const float o = acc_o[dt][rr] / fmaxf(lreg[rr], 1e-30f);
      const float uv = (float)qu[qrow * QS + 1536 + h * 64 + d];
      g[qrow * D_ + h * 64 + d] = (__bf16)(o / (1.f + __expf(-o)) * uv);
    }
  }
}

extern "C" void kernel_launch(void* const* d_in, const int* in_sizes, int n_in,
                              void* d_out, int out_size, void* d_ws, size_t ws_size,
                              hipStream_t stream) {
  const float* x     = (const float*)d_in[0];
  const float* w_qkv = (const float*)d_in[1];
  const float* b_qkv = (const float*)d_in[2];
  const float* w_u   = (const float*)d_in[3];
  const float* b_u   = (const float*)d_in[4];
  const float* w_out = (const float*)d_in[5];
  const float* b_out = (const float*)d_in[6];
  float* out = (float*)d_out;

  char* ws = (char*)d_ws;
  __bf16* xb   = (__bf16*)ws;                           //  8 MB
  __bf16* wcat = (__bf16*)(ws + 8388608);               //  2 MB [w_qkv;w_u]
  __bf16* wob  = (__bf16*)(ws + 10485760);              //  0.5 MB
  float*  bcat = (float*) (ws + 11010048);              //  8 KB
  __bf16* qu   = (__bf16*)(ws + 11018240);              // 32 MB [q|k|v|u]
  __bf16* gb   = (__bf16*)(ws + 44572672);              //  8 MB

  // one-time opt-in for 128 KB dynamic LDS (host-side attr, graph-safe)
  static bool attr_done = []() {
    hipFuncSetAttribute((const void*)gemm256,
                        hipFuncAttributeMaxDynamicSharedMemorySize, 131072);
    return true;
  }();
  (void)attr_done;

  cvt_pack<<<dim3(2688), dim3(256), 0, stream>>>(
      x, w_qkv, w_u, w_out, b_qkv, b_u, xb, wcat, wob, bcat);
  gemm256<<<dim3(32, 8), dim3(512), 131072, stream>>>(
      xb, wcat, bcat, qu, 8192, 2048, 512);
  attn_tile<<<dim3(L_ / 128, H_, B_), dim3(512), 0, stream>>>(qu, gb);
  gemm_out<<<dim3(128, 4), dim3(256), 0, stream>>>(
      gb, wob, b_out, out);
}

// Round 8
// 138.991 us; speedup vs baseline: 2.9929x; 1.0001x over previous
//
#include <hip/hip_runtime.h>
#include <hip/hip_bf16.h>

typedef __bf16 bf16x8 __attribute__((ext_vector_type(8)));
typedef float f32x4 __attribute__((ext_vector_type(4)));

#define B_ 4
#define L_ 2048
#define D_ 512
#define H_ 8
#define QS 2048
#define SP 72

#define SB0 __builtin_amdgcn_sched_barrier(0)
#define WAIT_VM(n) asm volatile("s_waitcnt vmcnt(" #n ")" ::: "memory")
#define WAIT_LGKM0 asm volatile("s_waitcnt lgkmcnt(0)" ::: "memory")

// async 16B global -> LDS (gfx950 global_load_lds_dwordx4)
__device__ __forceinline__ void gl16(const __bf16* g, __bf16* l) {
  __builtin_amdgcn_global_load_lds(
      (const __attribute__((address_space(1))) void*)g,
      (__attribute__((address_space(3))) void*)l, 16, 0, 0);
}

// f32 -> bf16 conversion + packing. vec8 regions:
// x[0,524288) wqkv[524288,622592) wu[622592,655360) wout[655360,688128)
// Also builds bcat[2048] = [b_qkv ; b_u] (f32) in block 0.
__global__ __launch_bounds__(256) void cvt_pack(
    const float* __restrict__ x, const float* __restrict__ wq,
    const float* __restrict__ wu, const float* __restrict__ wo,
    const float* __restrict__ bq, const float* __restrict__ bu,
    __bf16* __restrict__ xb, __bf16* __restrict__ wcat,
    __bf16* __restrict__ wob, float* __restrict__ bcat)
{
  const int idx8 = blockIdx.x * 256 + threadIdx.x;
  const float* src; __bf16* dst; size_t so, dof;
  if (idx8 < 524288)      { src = x;  dst = xb;   so = (size_t)idx8 * 8;            dof = so; }
  else if (idx8 < 622592) { src = wq; dst = wcat; so = (size_t)(idx8 - 524288) * 8; dof = so; }
  else if (idx8 < 655360) { src = wu; dst = wcat; so = (size_t)(idx8 - 622592) * 8; dof = so + 786432; }
  else                    { src = wo; dst = wob;  so = (size_t)(idx8 - 655360) * 8; dof = so; }
  const float4 lo = *(const float4*)(src + so);
  const float4 hi = *(const float4*)(src + so + 4);
  bf16x8 r;
  r[0] = (__bf16)lo.x; r[1] = (__bf16)lo.y; r[2] = (__bf16)lo.z; r[3] = (__bf16)lo.w;
  r[4] = (__bf16)hi.x; r[5] = (__bf16)hi.y; r[6] = (__bf16)hi.z; r[7] = (__bf16)hi.w;
  *(bf16x8*)(dst + dof) = r;
  if (blockIdx.x == 0) {
#pragma unroll
    for (int e = 0; e < 8; ++e) {
      const int col = threadIdx.x * 8 + e;
      bcat[col] = (col < 1536) ? bq[col] : bu[col - 1536];
    }
  }
}

// ---------------------------------------------------------------------------
// QKVU GEMM: counted-vmcnt pipelined 128x128 tile, bf16 out.
// qu[8192][2048] = xb[8192][512] @ wcat[2048][512]^T + bcat.
// 256 thr = 4 waves (2M x 2N), per-wave 64x64 (acc 4x4 f32x4 = 64 VGPR).
// LDS 64 KB (A 2x16K + B 2x16K, dbuf) -> 2 blocks/CU; grid 64x16 = 1024
// blocks = exactly 2 balanced scheduling waves. Rationale: at K=512 (8
// tiles) the 256^2/1-block-CU variant exposes its pipeline fill (2/8 tiles)
// and every barrier drain with no co-tenant; 2 blocks/CU hides them
// (r6 gemm_out datum: same structure reached ~860 TF on a 4.3 GF GEMM).
// Same schedule as r2-green: vmcnt(8) entry, stage kt+2 after WAR barrier,
// T2 swizzle both-sides, setprio, r7 peeled last tile with store interleave.
// Accumulation order per element unchanged (tiles asc, k-halves 0,1).
// ---------------------------------------------------------------------------
__global__ __launch_bounds__(256, 2) void gemm128(
    const __bf16* __restrict__ A, const __bf16* __restrict__ W,
    const float* __restrict__ bias, __bf16* __restrict__ C,
    int M, int N, int K)
{
  extern __shared__ char sm[];   // A: p*16384 (2x16K), B: 32768 + p*16384
  const int t = threadIdx.x;
  const int lane = t & 63;
  const int wave = t >> 6;
  const int wm = (wave >> 1) * 64;
  const int wn = (wave & 1) * 64;
  const int bm0 = blockIdx.x * 128;
  const int bn0 = blockIdx.y * 128;
  const int r = lane & 15, q = lane >> 4;
  const int nt = K >> 6;

  auto stage = [&](int kt, int p) {
#pragma unroll
    for (int j = 0; j < 4; ++j) {            // A: 1024 chunks, 4/thread
      const int c = t + j * 256;
      const int row = c >> 3;
      const int cs = (c & 7) ^ (row & 7);
      gl16(A + (size_t)(bm0 + row) * K + kt * 64 + cs * 8,
           (__bf16*)(sm + p * 16384) + c * 8);
    }
#pragma unroll
    for (int j = 0; j < 4; ++j) {            // B: 1024 chunks, 4/thread
      const int c = t + j * 256;
      const int row = c >> 3;
      const int cs = (c & 7) ^ (row & 7);
      gl16(W + (size_t)(bn0 + row) * K + kt * 64 + cs * 8,
           (__bf16*)(sm + 32768 + p * 16384) + c * 8);
    }
  };
  auto rdA = [&](int p, int mi, int ks) -> bf16x8 {
    const int row = wm + mi * 16 + r;
    const int byte = row * 128 + ((ks * 64 + q * 16) ^ ((row & 7) << 4));
    return *(const bf16x8*)(sm + p * 16384 + byte);
  };
  auto rdB = [&](int p, int ni, int ks) -> bf16x8 {
    const int row = wn + ni * 16 + r;
    const int byte = row * 128 + ((ks * 64 + q * 16) ^ ((row & 7) << 4));
    return *(const bf16x8*)(sm + 32768 + p * 16384 + byte);
  };

  f32x4 acc[4][4] = {};
  stage(0, 0);
  stage(1, 1);

  for (int kt = 0; kt < nt - 1; ++kt) {
    const int p = kt & 1;
    WAIT_VM(8);
    SB0; __builtin_amdgcn_s_barrier(); SB0;

    bf16x8 a[4][2], b01[2][2], b23[2][2];
#pragma unroll
    for (int mi = 0; mi < 4; ++mi) { a[mi][0] = rdA(p, mi, 0); a[mi][1] = rdA(p, mi, 1); }
#pragma unroll
    for (int ni = 0; ni < 2; ++ni) { b01[ni][0] = rdB(p, ni, 0); b01[ni][1] = rdB(p, ni, 1); }
    __builtin_amdgcn_s_setprio(1);
#pragma unroll
    for (int mi = 0; mi < 4; ++mi)
#pragma unroll
      for (int ni = 0; ni < 2; ++ni) {
        acc[mi][ni] = __builtin_amdgcn_mfma_f32_16x16x32_bf16(a[mi][0], b01[ni][0], acc[mi][ni], 0, 0, 0);
        acc[mi][ni] = __builtin_amdgcn_mfma_f32_16x16x32_bf16(a[mi][1], b01[ni][1], acc[mi][ni], 0, 0, 0);
      }
    __builtin_amdgcn_s_setprio(0);
#pragma unroll
    for (int ni = 0; ni < 2; ++ni) { b23[ni][0] = rdB(p, ni + 2, 0); b23[ni][1] = rdB(p, ni + 2, 1); }
    WAIT_LGKM0;                 // all buf-p reads retired (WAR)
    SB0; __builtin_amdgcn_s_barrier(); SB0;
    if (kt + 2 < nt) stage(kt + 2, p);
    __builtin_amdgcn_s_setprio(1);
#pragma unroll
    for (int mi = 0; mi < 4; ++mi)
#pragma unroll
      for (int ni = 0; ni < 2; ++ni) {
        acc[mi][ni + 2] = __builtin_amdgcn_mfma_f32_16x16x32_bf16(a[mi][0], b23[ni][0], acc[mi][ni + 2], 0, 0, 0);
        acc[mi][ni + 2] = __builtin_amdgcn_mfma_f32_16x16x32_bf16(a[mi][1], b23[ni][1], acc[mi][ni + 2], 0, 0, 0);
      }
    __builtin_amdgcn_s_setprio(0);
  }

  // ---- peeled last tile: interleave C-stores with remaining compute ----
  {
    const int p = (nt - 1) & 1;
    const int cc = lane & 15, cq = lane >> 4;
    WAIT_VM(0);
    SB0; __builtin_amdgcn_s_barrier(); SB0;

    float bv[4];
#pragma unroll
    for (int ni = 0; ni < 4; ++ni) bv[ni] = bias[bn0 + wn + ni * 16 + cc];

    auto st = [&](int mi, int ni) {
      const int gcol = bn0 + wn + ni * 16 + cc;
#pragma unroll
      for (int rr = 0; rr < 4; ++rr) {
        const int grow = bm0 + wm + mi * 16 + cq * 4 + rr;
        C[(size_t)grow * N + gcol] = (__bf16)(acc[mi][ni][rr] + bv[ni]);
      }
    };

    bf16x8 a[4][2], b01[2][2], b23[2][2];
#pragma unroll
    for (int mi = 0; mi < 4; ++mi) { a[mi][0] = rdA(p, mi, 0); a[mi][1] = rdA(p, mi, 1); }
#pragma unroll
    for (int ni = 0; ni < 2; ++ni) { b01[ni][0] = rdB(p, ni, 0); b01[ni][1] = rdB(p, ni, 1); }
    __builtin_amdgcn_s_setprio(1);
#pragma unroll
    for (int mi = 0; mi < 4; ++mi)
#pragma unroll
      for (int ni = 0; ni < 2; ++ni) {
        acc[mi][ni] = __builtin_amdgcn_mfma_f32_16x16x32_bf16(a[mi][0], b01[ni][0], acc[mi][ni], 0, 0, 0);
        acc[mi][ni] = __builtin_amdgcn_mfma_f32_16x16x32_bf16(a[mi][1], b01[ni][1], acc[mi][ni], 0, 0, 0);
      }
    __builtin_amdgcn_s_setprio(0);
#pragma unroll
    for (int mi = 0; mi < 4; ++mi)
#pragma unroll
      for (int ni = 0; ni < 2; ++ni) st(mi, ni);          // half 0 out

#pragma unroll
    for (int ni = 0; ni < 2; ++ni) { b23[ni][0] = rdB(p, ni + 2, 0); b23[ni][1] = rdB(p, ni + 2, 1); }
    __builtin_amdgcn_s_setprio(1);
#pragma unroll
    for (int mi = 0; mi < 4; ++mi)
#pragma unroll
      for (int ni = 0; ni < 2; ++ni) {
        acc[mi][ni + 2] = __builtin_amdgcn_mfma_f32_16x16x32_bf16(a[mi][0], b23[ni][0], acc[mi][ni + 2], 0, 0, 0);
        acc[mi][ni + 2] = __builtin_amdgcn_mfma_f32_16x16x32_bf16(a[mi][1], b23[ni][1], acc[mi][ni + 2], 0, 0, 0);
      }
    __builtin_amdgcn_s_setprio(0);
#pragma unroll
    for (int mi = 0; mi < 4; ++mi)
#pragma unroll
      for (int ni = 2; ni < 4; ++ni) st(mi, ni);          // half 1 out
  }
}

// ---------------------------------------------------------------------------
// Out-proj GEMM: counted-vmcnt pipelined 64x128 tile, f32 out (r7 green).
// ---------------------------------------------------------------------------
__global__ __launch_bounds__(256, 2) void gemm_out(
    const __bf16* __restrict__ A, const __bf16* __restrict__ W,
    const float* __restrict__ bias, float* __restrict__ C)
{
  __shared__ char sm[49152];   // A: p*8192 (2x8K), B: 16384 + p*16384 (2x16K)
  const int t = threadIdx.x;
  const int lane = t & 63;
  const int wave = t >> 6;
  const int wm = (wave >> 1) * 32;
  const int wn = (wave & 1) * 64;
  const int bm0 = blockIdx.x * 64;
  const int bn0 = blockIdx.y * 128;
  const int r = lane & 15, q = lane >> 4;
  const int K = 512, N = 512;

  auto stage = [&](int kt, int p) {
#pragma unroll
    for (int j = 0; j < 2; ++j) {            // A: 512 chunks, 2/thread
      const int c = t + j * 256;
      const int row = c >> 3;
      const int cs = (c & 7) ^ (row & 7);
      gl16(A + (size_t)(bm0 + row) * K + kt * 64 + cs * 8,
           (__bf16*)(sm + p * 8192) + c * 8);
    }
#pragma unroll
    for (int j = 0; j < 4; ++j) {            // B: 1024 chunks, 4/thread
      const int c = t + j * 256;
      const int row = c >> 3;
      const int cs = (c & 7) ^ (row & 7);
      gl16(W + (size_t)(bn0 + row) * K + kt * 64 + cs * 8,
           (__bf16*)(sm + 16384 + p * 16384) + c * 8);
    }
  };
  auto rdA = [&](int p, int mi, int ks) -> bf16x8 {
    const int row = wm + mi * 16 + r;
    const int byte = row * 128 + ((ks * 64 + q * 16) ^ ((row & 7) << 4));
    return *(const bf16x8*)(sm + p * 8192 + byte);
  };
  auto rdB = [&](int p, int ni, int ks) -> bf16x8 {
    const int row = wn + ni * 16 + r;
    const int byte = row * 128 + ((ks * 64 + q * 16) ^ ((row & 7) << 4));
    return *(const bf16x8*)(sm + 16384 + p * 16384 + byte);
  };

  f32x4 acc[2][4] = {};
  stage(0, 0);
  stage(1, 1);

  for (int kt = 0; kt < 7; ++kt) {
    const int p = kt & 1;
    WAIT_VM(6);
    SB0; __builtin_amdgcn_s_barrier(); SB0;

    bf16x8 a[2][2], b01[2][2], b23[2][2];
#pragma unroll
    for (int mi = 0; mi < 2; ++mi) { a[mi][0] = rdA(p, mi, 0); a[mi][1] = rdA(p, mi, 1); }
#pragma unroll
    for (int ni = 0; ni < 2; ++ni) { b01[ni][0] = rdB(p, ni, 0); b01[ni][1] = rdB(p, ni, 1); }
    __builtin_amdgcn_s_setprio(1);
#pragma unroll
    for (int mi = 0; mi < 2; ++mi)
#pragma unroll
      for (int ni = 0; ni < 2; ++ni) {
        acc[mi][ni] = __builtin_amdgcn_mfma_f32_16x16x32_bf16(a[mi][0], b01[ni][0], acc[mi][ni], 0, 0, 0);
        acc[mi][ni] = __builtin_amdgcn_mfma_f32_16x16x32_bf16(a[mi][1], b01[ni][1], acc[mi][ni], 0, 0, 0);
      }
    __builtin_amdgcn_s_setprio(0);
#pragma unroll
    for (int ni = 0; ni < 2; ++ni) { b23[ni][0] = rdB(p, ni + 2, 0); b23[ni][1] = rdB(p, ni + 2, 1); }
    WAIT_LGKM0;                 // all buf-p reads retired
    SB0; __builtin_amdgcn_s_barrier(); SB0;
    if (kt + 2 < 8) stage(kt + 2, p);
    __builtin_amdgcn_s_setprio(1);
#pragma unroll
    for (int mi = 0; mi < 2; ++mi)
#pragma unroll
      for (int ni = 0; ni < 2; ++ni) {
        acc[mi][ni + 2] = __builtin_amdgcn_mfma_f32_16x16x32_bf16(a[mi][0], b23[ni][0], acc[mi][ni + 2], 0, 0, 0);
        acc[mi][ni + 2] = __builtin_amdgcn_mfma_f32_16x16x32_bf16(a[mi][1], b23[ni][1], acc[mi][ni + 2], 0, 0, 0);
      }
    __builtin_amdgcn_s_setprio(0);
  }

  // ---- peeled last tile (kt=7, p=1): stores interleaved ----
  {
    const int p = 1;
    const int cc = lane & 15, cq = lane >> 4;
    WAIT_VM(0);
    SB0; __builtin_amdgcn_s_barrier(); SB0;

    float bv[4];
#pragma unroll
    for (int ni = 0; ni < 4; ++ni) bv[ni] = bias[bn0 + wn + ni * 16 + cc];

    auto st = [&](int mi, int ni) {
      const int gcol = bn0 + wn + ni * 16 + cc;
#pragma unroll
      for (int rr = 0; rr < 4; ++rr) {
        const int grow = bm0 + wm + mi * 16 + cq * 4 + rr;
        C[(size_t)grow * N + gcol] = acc[mi][ni][rr] + bv[ni];
      }
    };

    bf16x8 a[2][2], b01[2][2], b23[2][2];
#pragma unroll
    for (int mi = 0; mi < 2; ++mi) { a[mi][0] = rdA(p, mi, 0); a[mi][1] = rdA(p, mi, 1); }
#pragma unroll
    for (int ni = 0; ni < 2; ++ni) { b01[ni][0] = rdB(p, ni, 0); b01[ni][1] = rdB(p, ni, 1); }
    __builtin_amdgcn_s_setprio(1);
#pragma unroll
    for (int mi = 0; mi < 2; ++mi)
#pragma unroll
      for (int ni = 0; ni < 2; ++ni) {
        acc[mi][ni] = __builtin_amdgcn_mfma_f32_16x16x32_bf16(a[mi][0], b01[ni][0], acc[mi][ni], 0, 0, 0);
        acc[mi][ni] = __builtin_amdgcn_mfma_f32_16x16x32_bf16(a[mi][1], b01[ni][1], acc[mi][ni], 0, 0, 0);
      }
    __builtin_amdgcn_s_setprio(0);
#pragma unroll
    for (int mi = 0; mi < 2; ++mi)
#pragma unroll
      for (int ni = 0; ni < 2; ++ni) st(mi, ni);          // half 0 out

#pragma unroll
    for (int ni = 0; ni < 2; ++ni) { b23[ni][0] = rdB(p, ni + 2, 0); b23[ni][1] = rdB(p, ni + 2, 1); }
    __builtin_amdgcn_s_setprio(1);
#pragma unroll
    for (int mi = 0; mi < 2; ++mi)
#pragma unroll
      for (int ni = 0; ni < 2; ++ni) {
        acc[mi][ni + 2] = __builtin_amdgcn_mfma_f32_16x16x32_bf16(a[mi][0], b23[ni][0], acc[mi][ni + 2], 0, 0, 0);
        acc[mi][ni + 2] = __builtin_amdgcn_mfma_f32_16x16x32_bf16(a[mi][1], b23[ni][1], acc[mi][ni + 2], 0, 0, 0);
      }
    __builtin_amdgcn_s_setprio(0);
#pragma unroll
    for (int mi = 0; mi < 2; ++mi)
#pragma unroll
      for (int ni = 2; ni < 4; ++ni) st(mi, ni);          // half 1 out
  }
}

// Flash-style MFMA attention, QBLK=128 / 512 threads / 8 waves (r5 green).
__global__ __launch_bounds__(512) void attn_tile(
    const __bf16* __restrict__ qu,   // [B*L][2048]  q|k|v|u
    __bf16* __restrict__ g)          // [B*L][512]
{
  const int qt = blockIdx.x, h = blockIdx.y, b = blockIdx.z;
  const int t = threadIdx.x;
  const int lane = t & 63;
  const int w = t >> 6;                    // 8 waves, 16 q-rows each
  const int q0 = qt * 128, qmax = q0 + 127;
  const size_t bL = (size_t)b * L_;

  __shared__ __bf16 lK[4096];        // [64][64] bf16, XOR-swizzled rows (8KB)
  __shared__ __bf16 lV[64 * SP];     // V^T: [d 64][key 64] stride 72 (9KB)
  __shared__ __bf16 Pb[128 * SP];    // P: [q 128][key 64] stride 72 (18KB)

  const int cq = lane >> 4, cc = lane & 15;
  const int krow_st = t >> 3, kgb8 = t & 7;   // K-staging: 64 rows x 8 chunks

  bf16x8 aq0, aq1;
  {
    const __bf16* qsrc = qu + (bL + q0 + w * 16 + cc) * QS + h * 64 + cq * 8;
    aq0 = *(const bf16x8*)qsrc;
    aq1 = *(const bf16x8*)(qsrc + 32);
  }

  float mreg[4], lreg[4];
#pragma unroll
  for (int rr = 0; rr < 4; ++rr) { mreg[rr] = -1e30f; lreg[rr] = 0.f; }
  f32x4 acc_o[4] = {};

  int clist[8]; int ncl = 0;
  clist[ncl++] = 0;
  if (qmax >= 64) clist[ncl++] = 64;
  {
    int lo = 1984 - qmax; if (lo < 0) lo = 0; lo &= ~63;
    const int hik = min(qmax, 2048 - q0);
    for (int c = lo; c <= hik; c += 64)
      if (c >= 128) clist[ncl++] = c;
  }

  // prologue: tile-0 K/V into registers (T14 pipeline)
  bf16x8 k0r, var;
  {
    const __bf16* src = qu + (bL + clist[0] + krow_st) * QS + 512 + h * 64;
    k0r = *(const bf16x8*)(src + kgb8 * 8);
    const __bf16* vsrc = qu + (bL + clist[0] + lane) * QS + 1024 + h * 64 + w * 8;
    var = *(const bf16x8*)vsrc;
  }

  for (int ci = 0; ci < ncl; ++ci) {
    const int c0 = clist[ci];
    WAIT_VM(0);                                 // this tile's K/V landed
    SB0; __builtin_amdgcn_s_barrier(); SB0;     // WAR: prior tile's reads done
    {
      char* lkb = (char*)lK;
      const int sw = (krow_st & 7) << 4;
      *(bf16x8*)(lkb + ((krow_st * 128 + kgb8 * 16) ^ sw)) = k0r;
#pragma unroll
      for (int e = 0; e < 8; ++e)
        lV[(w * 8 + e) * SP + lane] = var[e];
    }
    if (ci + 1 < ncl) {                         // issue next tile's loads
      const int cn = clist[ci + 1];
      const __bf16* src = qu + (bL + cn + krow_st) * QS + 512 + h * 64;
      k0r = *(const bf16x8*)(src + kgb8 * 8);
      const __bf16* vsrc = qu + (bL + cn + lane) * QS + 1024 + h * 64 + w * 8;
      var = *(const bf16x8*)vsrc;
    }
    WAIT_LGKM0;                                 // my ds_writes retired
    SB0; __builtin_amdgcn_s_barrier(); SB0;     // RAW: all writes visible

    f32x4 s[4];
    {
      const char* lkb = (const char*)lK;
#pragma unroll
      for (int nt = 0; nt < 4; ++nt) {
        const int krow = nt * 16 + cc;
        const int sw = (krow & 7) << 4;
        bf16x8 bk0 = *(const bf16x8*)(lkb + ((krow * 128 + cq * 16) ^ sw));
        bf16x8 bk1 = *(const bf16x8*)(lkb + ((krow * 128 + 64 + cq * 16) ^ sw));
        f32x4 a = {};
        a = __builtin_amdgcn_mfma_f32_16x16x32_bf16(aq0, bk0, a, 0, 0, 0);
        a = __builtin_amdgcn_mfma_f32_16x16x32_bf16(aq1, bk1, a, 0, 0, 0);
        s[nt] = a;
      }
    }

#pragma unroll
    for (int nt = 0; nt < 4; ++nt) {
#pragma unroll
      for (int rr = 0; rr < 4; ++rr) {
        const int i = q0 + w * 16 + cq * 4 + rr;
        const int j = c0 + nt * 16 + cc;
        const int ij = i + j;
        const bool valid = (j <= i) &&
            ((ij >= 1984 && ij <= 2048) || (j <= 64 && ij <= 2048));
        s[nt][rr] = valid ? s[nt][rr] * 0.125f : -1e30f;
      }
    }

    f32x4 pm;
#pragma unroll
    for (int rr = 0; rr < 4; ++rr)
      pm[rr] = fmaxf(fmaxf(s[0][rr], s[1][rr]), fmaxf(s[2][rr], s[3][rr]));
#pragma unroll
    for (int m = 1; m < 16; m <<= 1) {
#pragma unroll
      for (int rr = 0; rr < 4; ++rr)
        pm[rr] = fmaxf(pm[rr], __shfl_xor(pm[rr], m, 64));
    }
    float corr[4];
#pragma unroll
    for (int rr = 0; rr < 4; ++rr) {
      const float nm = fmaxf(mreg[rr], pm[rr]);
      corr[rr] = __expf(mreg[rr] - nm);
      mreg[rr] = nm;
    }

    f32x4 ps = {};
#pragma unroll
    for (int nt = 0; nt < 4; ++nt) {
#pragma unroll
      for (int rr = 0; rr < 4; ++rr) {
        const float p = __expf(s[nt][rr] - mreg[rr]);
        ps[rr] += p;
        Pb[(w * 16 + cq * 4 + rr) * SP + nt * 16 + cc] = (__bf16)p;
      }
    }
#pragma unroll
    for (int m = 1; m < 16; m <<= 1) {
#pragma unroll
      for (int rr = 0; rr < 4; ++rr)
        ps[rr] += __shfl_xor(ps[rr], m, 64);
    }
#pragma unroll
    for (int rr = 0; rr < 4; ++rr) lreg[rr] = lreg[rr] * corr[rr] + ps[rr];

    {
      bf16x8 pa0 = *(const bf16x8*)(Pb + (w * 16 + cc) * SP + cq * 8);
      bf16x8 pa1 = *(const bf16x8*)(Pb + (w * 16 + cc) * SP + 32 + cq * 8);
#pragma unroll
      for (int dt = 0; dt < 4; ++dt) {
#pragma unroll
        for (int rr = 0; rr < 4; ++rr) acc_o[dt][rr] *= corr[rr];
        bf16x8 vb0 = *(const bf16x8*)(lV + (dt * 16 + cc) * SP + cq * 8);
        bf16x8 vb1 = *(const bf16x8*)(lV + (dt * 16 + cc) * SP + 32 + cq * 8);
        acc_o[dt] = __builtin_amdgcn_mfma_f32_16x16x32_bf16(pa0, vb0, acc_o[dt], 0, 0, 0);
        acc_o[dt] = __builtin_amdgcn_mfma_f32_16x16x32_bf16(pa1, vb1, acc_o[dt], 0, 0, 0);
      }
    }
  }

  // epilogue: register state only
#pragma unroll
  for (int dt = 0; dt < 4; ++dt) {
#pragma unroll
    for (int rr = 0; rr < 4; ++rr) {
      const int row16 = cq * 4 + rr;
      const size_t qrow = bL + q0 + w * 16 + row16;
      const int d = dt * 16 + cc;
      const float o = acc_o[dt][rr] / fmaxf(lreg[rr], 1e-30f);
      const float uv = (float)qu[qrow * QS + 1536 + h * 64 + d];
      g[qrow * D_ + h * 64 + d] = (__bf16)(o / (1.f + __expf(-o)) * uv);
    }
  }
}

extern "C" void kernel_launch(void* const* d_in, const int* in_sizes, int n_in,
                              void* d_out, int out_size, void* d_ws, size_t ws_size,
                              hipStream_t stream) {
  const float* x     = (const float*)d_in[0];
  const float* w_qkv = (const float*)d_in[1];
  const float* b_qkv = (const float*)d_in[2];
  const float* w_u   = (const float*)d_in[3];
  const float* b_u   = (const float*)d_in[4];
  const float* w_out = (const float*)d_in[5];
  const float* b_out = (const float*)d_in[6];
  float* out = (float*)d_out;

  char* ws = (char*)d_ws;
  __bf16* xb   = (__bf16*)ws;                           //  8 MB
  __bf16* wcat = (__bf16*)(ws + 8388608);               //  2 MB [w_qkv;w_u]
  __bf16* wob  = (__bf16*)(ws + 10485760);              //  0.5 MB
  float*  bcat = (float*) (ws + 11010048);              //  8 KB
  __bf16* qu   = (__bf16*)(ws + 11018240);              // 32 MB [q|k|v|u]
  __bf16* gb   = (__bf16*)(ws + 44572672);              //  8 MB

  // one-time opt-in for 64 KB dynamic LDS (host-side attr, graph-safe)
  static bool attr_done = []() {
    hipFuncSetAttribute((const void*)gemm128,
                        hipFuncAttributeMaxDynamicSharedMemorySize, 65536);
    return true;
  }();
  (void)attr_done;

  cvt_pack<<<dim3(2688), dim3(256), 0, stream>>>(
      x, w_qkv, w_u, w_out, b_qkv, b_u, xb, wcat, wob, bcat);
  gemm128<<<dim3(64, 16), dim3(256), 65536, stream>>>(
      xb, wcat, bcat, qu, 8192, 2048, 512);
  attn_tile<<<dim3(L_ / 128, H_, B_), dim3(512), 0, stream>>>(qu, gb);
  gemm_out<<<dim3(128, 4), dim3(256), 0, stream>>>(
      gb, wob, b_out, out);
}

// Round 9
// 135.375 us; speedup vs baseline: 3.0729x; 1.0267x over previous
//
#include <hip/hip_runtime.h>
#include <hip/hip_bf16.h>

typedef __bf16 bf16x8 __attribute__((ext_vector_type(8)));
typedef float f32x4 __attribute__((ext_vector_type(4)));

#define B_ 4
#define L_ 2048
#define D_ 512
#define H_ 8
#define QS 2048
#define SP 72

#define SB0 __builtin_amdgcn_sched_barrier(0)
#define WAIT_VM(n) asm volatile("s_waitcnt vmcnt(" #n ")" ::: "memory")
#define WAIT_LGKM0 asm volatile("s_waitcnt lgkmcnt(0)" ::: "memory")

// async 16B global -> LDS (gfx950 global_load_lds_dwordx4)
__device__ __forceinline__ void gl16(const __bf16* g, __bf16* l) {
  __builtin_amdgcn_global_load_lds(
      (const __attribute__((address_space(1))) void*)g,
      (__attribute__((address_space(3))) void*)l, 16, 0, 0);
}

// f32 -> bf16 conversion + packing. vec8 regions:
// x[0,524288) wqkv[524288,622592) wu[622592,655360) wout[655360,688128)
// Also builds bcat[2048] = [b_qkv ; b_u] (f32) in block 0.
__global__ __launch_bounds__(256) void cvt_pack(
    const float* __restrict__ x, const float* __restrict__ wq,
    const float* __restrict__ wu, const float* __restrict__ wo,
    const float* __restrict__ bq, const float* __restrict__ bu,
    __bf16* __restrict__ xb, __bf16* __restrict__ wcat,
    __bf16* __restrict__ wob, float* __restrict__ bcat)
{
  const int idx8 = blockIdx.x * 256 + threadIdx.x;
  const float* src; __bf16* dst; size_t so, dof;
  if (idx8 < 524288)      { src = x;  dst = xb;   so = (size_t)idx8 * 8;            dof = so; }
  else if (idx8 < 622592) { src = wq; dst = wcat; so = (size_t)(idx8 - 524288) * 8; dof = so; }
  else if (idx8 < 655360) { src = wu; dst = wcat; so = (size_t)(idx8 - 622592) * 8; dof = so + 786432; }
  else                    { src = wo; dst = wob;  so = (size_t)(idx8 - 655360) * 8; dof = so; }
  const float4 lo = *(const float4*)(src + so);
  const float4 hi = *(const float4*)(src + so + 4);
  bf16x8 r;
  r[0] = (__bf16)lo.x; r[1] = (__bf16)lo.y; r[2] = (__bf16)lo.z; r[3] = (__bf16)lo.w;
  r[4] = (__bf16)hi.x; r[5] = (__bf16)hi.y; r[6] = (__bf16)hi.z; r[7] = (__bf16)hi.w;
  *(bf16x8*)(dst + dof) = r;
  if (blockIdx.x == 0) {
#pragma unroll
    for (int e = 0; e < 8; ++e) {
      const int col = threadIdx.x * 8 + e;
      bcat[col] = (col < 1536) ? bq[col] : bu[col - 1536];
    }
  }
}

// ---------------------------------------------------------------------------
// QKVU GEMM: counted-vmcnt pipelined 128x128 tile, bf16 out (r8 green).
// ---------------------------------------------------------------------------
__global__ __launch_bounds__(256, 2) void gemm128(
    const __bf16* __restrict__ A, const __bf16* __restrict__ W,
    const float* __restrict__ bias, __bf16* __restrict__ C,
    int M, int N, int K)
{
  extern __shared__ char sm[];   // A: p*16384 (2x16K), B: 32768 + p*16384
  const int t = threadIdx.x;
  const int lane = t & 63;
  const int wave = t >> 6;
  const int wm = (wave >> 1) * 64;
  const int wn = (wave & 1) * 64;
  const int bm0 = blockIdx.x * 128;
  const int bn0 = blockIdx.y * 128;
  const int r = lane & 15, q = lane >> 4;
  const int nt = K >> 6;

  auto stage = [&](int kt, int p) {
#pragma unroll
    for (int j = 0; j < 4; ++j) {            // A: 1024 chunks, 4/thread
      const int c = t + j * 256;
      const int row = c >> 3;
      const int cs = (c & 7) ^ (row & 7);
      gl16(A + (size_t)(bm0 + row) * K + kt * 64 + cs * 8,
           (__bf16*)(sm + p * 16384) + c * 8);
    }
#pragma unroll
    for (int j = 0; j < 4; ++j) {            // B: 1024 chunks, 4/thread
      const int c = t + j * 256;
      const int row = c >> 3;
      const int cs = (c & 7) ^ (row & 7);
      gl16(W + (size_t)(bn0 + row) * K + kt * 64 + cs * 8,
           (__bf16*)(sm + 32768 + p * 16384) + c * 8);
    }
  };
  auto rdA = [&](int p, int mi, int ks) -> bf16x8 {
    const int row = wm + mi * 16 + r;
    const int byte = row * 128 + ((ks * 64 + q * 16) ^ ((row & 7) << 4));
    return *(const bf16x8*)(sm + p * 16384 + byte);
  };
  auto rdB = [&](int p, int ni, int ks) -> bf16x8 {
    const int row = wn + ni * 16 + r;
    const int byte = row * 128 + ((ks * 64 + q * 16) ^ ((row & 7) << 4));
    return *(const bf16x8*)(sm + 32768 + p * 16384 + byte);
  };

  f32x4 acc[4][4] = {};
  stage(0, 0);
  stage(1, 1);

  for (int kt = 0; kt < nt - 1; ++kt) {
    const int p = kt & 1;
    WAIT_VM(8);
    SB0; __builtin_amdgcn_s_barrier(); SB0;

    bf16x8 a[4][2], b01[2][2], b23[2][2];
#pragma unroll
    for (int mi = 0; mi < 4; ++mi) { a[mi][0] = rdA(p, mi, 0); a[mi][1] = rdA(p, mi, 1); }
#pragma unroll
    for (int ni = 0; ni < 2; ++ni) { b01[ni][0] = rdB(p, ni, 0); b01[ni][1] = rdB(p, ni, 1); }
    __builtin_amdgcn_s_setprio(1);
#pragma unroll
    for (int mi = 0; mi < 4; ++mi)
#pragma unroll
      for (int ni = 0; ni < 2; ++ni) {
        acc[mi][ni] = __builtin_amdgcn_mfma_f32_16x16x32_bf16(a[mi][0], b01[ni][0], acc[mi][ni], 0, 0, 0);
        acc[mi][ni] = __builtin_amdgcn_mfma_f32_16x16x32_bf16(a[mi][1], b01[ni][1], acc[mi][ni], 0, 0, 0);
      }
    __builtin_amdgcn_s_setprio(0);
#pragma unroll
    for (int ni = 0; ni < 2; ++ni) { b23[ni][0] = rdB(p, ni + 2, 0); b23[ni][1] = rdB(p, ni + 2, 1); }
    WAIT_LGKM0;                 // all buf-p reads retired (WAR)
    SB0; __builtin_amdgcn_s_barrier(); SB0;
    if (kt + 2 < nt) stage(kt + 2, p);
    __builtin_amdgcn_s_setprio(1);
#pragma unroll
    for (int mi = 0; mi < 4; ++mi)
#pragma unroll
      for (int ni = 0; ni < 2; ++ni) {
        acc[mi][ni + 2] = __builtin_amdgcn_mfma_f32_16x16x32_bf16(a[mi][0], b23[ni][0], acc[mi][ni + 2], 0, 0, 0);
        acc[mi][ni + 2] = __builtin_amdgcn_mfma_f32_16x16x32_bf16(a[mi][1], b23[ni][1], acc[mi][ni + 2], 0, 0, 0);
      }
    __builtin_amdgcn_s_setprio(0);
  }

  // ---- peeled last tile: interleave C-stores with remaining compute ----
  {
    const int p = (nt - 1) & 1;
    const int cc = lane & 15, cq = lane >> 4;
    WAIT_VM(0);
    SB0; __builtin_amdgcn_s_barrier(); SB0;

    float bv[4];
#pragma unroll
    for (int ni = 0; ni < 4; ++ni) bv[ni] = bias[bn0 + wn + ni * 16 + cc];

    auto st = [&](int mi, int ni) {
      const int gcol = bn0 + wn + ni * 16 + cc;
#pragma unroll
      for (int rr = 0; rr < 4; ++rr) {
        const int grow = bm0 + wm + mi * 16 + cq * 4 + rr;
        C[(size_t)grow * N + gcol] = (__bf16)(acc[mi][ni][rr] + bv[ni]);
      }
    };

    bf16x8 a[4][2], b01[2][2], b23[2][2];
#pragma unroll
    for (int mi = 0; mi < 4; ++mi) { a[mi][0] = rdA(p, mi, 0); a[mi][1] = rdA(p, mi, 1); }
#pragma unroll
    for (int ni = 0; ni < 2; ++ni) { b01[ni][0] = rdB(p, ni, 0); b01[ni][1] = rdB(p, ni, 1); }
    __builtin_amdgcn_s_setprio(1);
#pragma unroll
    for (int mi = 0; mi < 4; ++mi)
#pragma unroll
      for (int ni = 0; ni < 2; ++ni) {
        acc[mi][ni] = __builtin_amdgcn_mfma_f32_16x16x32_bf16(a[mi][0], b01[ni][0], acc[mi][ni], 0, 0, 0);
        acc[mi][ni] = __builtin_amdgcn_mfma_f32_16x16x32_bf16(a[mi][1], b01[ni][1], acc[mi][ni], 0, 0, 0);
      }
    __builtin_amdgcn_s_setprio(0);
#pragma unroll
    for (int mi = 0; mi < 4; ++mi)
#pragma unroll
      for (int ni = 0; ni < 2; ++ni) st(mi, ni);          // half 0 out

#pragma unroll
    for (int ni = 0; ni < 2; ++ni) { b23[ni][0] = rdB(p, ni + 2, 0); b23[ni][1] = rdB(p, ni + 2, 1); }
    __builtin_amdgcn_s_setprio(1);
#pragma unroll
    for (int mi = 0; mi < 4; ++mi)
#pragma unroll
      for (int ni = 0; ni < 2; ++ni) {
        acc[mi][ni + 2] = __builtin_amdgcn_mfma_f32_16x16x32_bf16(a[mi][0], b23[ni][0], acc[mi][ni + 2], 0, 0, 0);
        acc[mi][ni + 2] = __builtin_amdgcn_mfma_f32_16x16x32_bf16(a[mi][1], b23[ni][1], acc[mi][ni + 2], 0, 0, 0);
      }
    __builtin_amdgcn_s_setprio(0);
#pragma unroll
    for (int mi = 0; mi < 4; ++mi)
#pragma unroll
      for (int ni = 2; ni < 4; ++ni) st(mi, ni);          // half 1 out
  }
}

// ---------------------------------------------------------------------------
// Out-proj GEMM: counted-vmcnt pipelined 64x128 tile, f32 out (r7 green).
// ---------------------------------------------------------------------------
__global__ __launch_bounds__(256, 2) void gemm_out(
    const __bf16* __restrict__ A, const __bf16* __restrict__ W,
    const float* __restrict__ bias, float* __restrict__ C)
{
  __shared__ char sm[49152];   // A: p*8192 (2x8K), B: 16384 + p*16384 (2x16K)
  const int t = threadIdx.x;
  const int lane = t & 63;
  const int wave = t >> 6;
  const int wm = (wave >> 1) * 32;
  const int wn = (wave & 1) * 64;
  const int bm0 = blockIdx.x * 64;
  const int bn0 = blockIdx.y * 128;
  const int r = lane & 15, q = lane >> 4;
  const int K = 512, N = 512;

  auto stage = [&](int kt, int p) {
#pragma unroll
    for (int j = 0; j < 2; ++j) {            // A: 512 chunks, 2/thread
      const int c = t + j * 256;
      const int row = c >> 3;
      const int cs = (c & 7) ^ (row & 7);
      gl16(A + (size_t)(bm0 + row) * K + kt * 64 + cs * 8,
           (__bf16*)(sm + p * 8192) + c * 8);
    }
#pragma unroll
    for (int j = 0; j < 4; ++j) {            // B: 1024 chunks, 4/thread
      const int c = t + j * 256;
      const int row = c >> 3;
      const int cs = (c & 7) ^ (row & 7);
      gl16(W + (size_t)(bn0 + row) * K + kt * 64 + cs * 8,
           (__bf16*)(sm + 16384 + p * 16384) + c * 8);
    }
  };
  auto rdA = [&](int p, int mi, int ks) -> bf16x8 {
    const int row = wm + mi * 16 + r;
    const int byte = row * 128 + ((ks * 64 + q * 16) ^ ((row & 7) << 4));
    return *(const bf16x8*)(sm + p * 8192 + byte);
  };
  auto rdB = [&](int p, int ni, int ks) -> bf16x8 {
    const int row = wn + ni * 16 + r;
    const int byte = row * 128 + ((ks * 64 + q * 16) ^ ((row & 7) << 4));
    return *(const bf16x8*)(sm + 16384 + p * 16384 + byte);
  };

  f32x4 acc[2][4] = {};
  stage(0, 0);
  stage(1, 1);

  for (int kt = 0; kt < 7; ++kt) {
    const int p = kt & 1;
    WAIT_VM(6);
    SB0; __builtin_amdgcn_s_barrier(); SB0;

    bf16x8 a[2][2], b01[2][2], b23[2][2];
#pragma unroll
    for (int mi = 0; mi < 2; ++mi) { a[mi][0] = rdA(p, mi, 0); a[mi][1] = rdA(p, mi, 1); }
#pragma unroll
    for (int ni = 0; ni < 2; ++ni) { b01[ni][0] = rdB(p, ni, 0); b01[ni][1] = rdB(p, ni, 1); }
    __builtin_amdgcn_s_setprio(1);
#pragma unroll
    for (int mi = 0; mi < 2; ++mi)
#pragma unroll
      for (int ni = 0; ni < 2; ++ni) {
        acc[mi][ni] = __builtin_amdgcn_mfma_f32_16x16x32_bf16(a[mi][0], b01[ni][0], acc[mi][ni], 0, 0, 0);
        acc[mi][ni] = __builtin_amdgcn_mfma_f32_16x16x32_bf16(a[mi][1], b01[ni][1], acc[mi][ni], 0, 0, 0);
      }
    __builtin_amdgcn_s_setprio(0);
#pragma unroll
    for (int ni = 0; ni < 2; ++ni) { b23[ni][0] = rdB(p, ni + 2, 0); b23[ni][1] = rdB(p, ni + 2, 1); }
    WAIT_LGKM0;                 // all buf-p reads retired
    SB0; __builtin_amdgcn_s_barrier(); SB0;
    if (kt + 2 < 8) stage(kt + 2, p);
    __builtin_amdgcn_s_setprio(1);
#pragma unroll
    for (int mi = 0; mi < 2; ++mi)
#pragma unroll
      for (int ni = 0; ni < 2; ++ni) {
        acc[mi][ni + 2] = __builtin_amdgcn_mfma_f32_16x16x32_bf16(a[mi][0], b23[ni][0], acc[mi][ni + 2], 0, 0, 0);
        acc[mi][ni + 2] = __builtin_amdgcn_mfma_f32_16x16x32_bf16(a[mi][1], b23[ni][1], acc[mi][ni + 2], 0, 0, 0);
      }
    __builtin_amdgcn_s_setprio(0);
  }

  // ---- peeled last tile (kt=7, p=1): stores interleaved ----
  {
    const int p = 1;
    const int cc = lane & 15, cq = lane >> 4;
    WAIT_VM(0);
    SB0; __builtin_amdgcn_s_barrier(); SB0;

    float bv[4];
#pragma unroll
    for (int ni = 0; ni < 4; ++ni) bv[ni] = bias[bn0 + wn + ni * 16 + cc];

    auto st = [&](int mi, int ni) {
      const int gcol = bn0 + wn + ni * 16 + cc;
#pragma unroll
      for (int rr = 0; rr < 4; ++rr) {
        const int grow = bm0 + wm + mi * 16 + cq * 4 + rr;
        C[(size_t)grow * N + gcol] = acc[mi][ni][rr] + bv[ni];
      }
    };

    bf16x8 a[2][2], b01[2][2], b23[2][2];
#pragma unroll
    for (int mi = 0; mi < 2; ++mi) { a[mi][0] = rdA(p, mi, 0); a[mi][1] = rdA(p, mi, 1); }
#pragma unroll
    for (int ni = 0; ni < 2; ++ni) { b01[ni][0] = rdB(p, ni, 0); b01[ni][1] = rdB(p, ni, 1); }
    __builtin_amdgcn_s_setprio(1);
#pragma unroll
    for (int mi = 0; mi < 2; ++mi)
#pragma unroll
      for (int ni = 0; ni < 2; ++ni) {
        acc[mi][ni] = __builtin_amdgcn_mfma_f32_16x16x32_bf16(a[mi][0], b01[ni][0], acc[mi][ni], 0, 0, 0);
        acc[mi][ni] = __builtin_amdgcn_mfma_f32_16x16x32_bf16(a[mi][1], b01[ni][1], acc[mi][ni], 0, 0, 0);
      }
    __builtin_amdgcn_s_setprio(0);
#pragma unroll
    for (int mi = 0; mi < 2; ++mi)
#pragma unroll
      for (int ni = 0; ni < 2; ++ni) st(mi, ni);          // half 0 out

#pragma unroll
    for (int ni = 0; ni < 2; ++ni) { b23[ni][0] = rdB(p, ni + 2, 0); b23[ni][1] = rdB(p, ni + 2, 1); }
    __builtin_amdgcn_s_setprio(1);
#pragma unroll
    for (int mi = 0; mi < 2; ++mi)
#pragma unroll
      for (int ni = 0; ni < 2; ++ni) {
        acc[mi][ni + 2] = __builtin_amdgcn_mfma_f32_16x16x32_bf16(a[mi][0], b23[ni][0], acc[mi][ni + 2], 0, 0, 0);
        acc[mi][ni + 2] = __builtin_amdgcn_mfma_f32_16x16x32_bf16(a[mi][1], b23[ni][1], acc[mi][ni + 2], 0, 0, 0);
      }
    __builtin_amdgcn_s_setprio(0);
#pragma unroll
    for (int mi = 0; mi < 2; ++mi)
#pragma unroll
      for (int ni = 2; ni < 4; ++ni) st(mi, ni);          // half 1 out
  }
}

// Flash-style MFMA attention, QBLK=128 / 512 threads / 8 waves.
// r9 changes (all block-uniform, bit-identical values):
//  - Q pre-scaled by 0.125 at load (exact: pow2 exponent shift in bf16/f32)
//    -> drops the per-element s*0.125.
//  - Tile-64 THIN path (qmax<=1856, no band overlap): only column j=64 is
//    valid -> QK nt=0 only (2 MFMA), P slots 16..31 zeroed, PV k=0..31 half
//    (4 MFMA). Invalid cols contribute exp(-1e30)=0 exactly, as before.
//  - Mask fast paths: tile 0 fully-valid skip (64<=q0, qmax+63<=2048);
//    band tiles (c0>=128) use 3-term band-only mask.
__global__ __launch_bounds__(512) void attn_tile(
    const __bf16* __restrict__ qu,   // [B*L][2048]  q|k|v|u
    __bf16* __restrict__ g)          // [B*L][512]
{
  const int qt = blockIdx.x, h = blockIdx.y, b = blockIdx.z;
  const int t = threadIdx.x;
  const int lane = t & 63;
  const int w = t >> 6;                    // 8 waves, 16 q-rows each
  const int q0 = qt * 128, qmax = q0 + 127;
  const size_t bL = (size_t)b * L_;

  __shared__ __bf16 lK[4096];        // [64][64] bf16, XOR-swizzled rows (8KB)
  __shared__ __bf16 lV[64 * SP];     // V^T: [d 64][key 64] stride 72 (9KB)
  __shared__ __bf16 Pb[128 * SP];    // P: [q 128][key 64] stride 72 (18KB)

  const int cq = lane >> 4, cc = lane & 15;
  const int krow_st = t >> 3, kgb8 = t & 7;   // K-staging: 64 rows x 8 chunks

  // Q fragments, pre-scaled by 1/sqrt(HD)=0.125 (exact pow2 scale)
  bf16x8 aq0, aq1;
  {
    const __bf16* qsrc = qu + (bL + q0 + w * 16 + cc) * QS + h * 64 + cq * 8;
    bf16x8 t0 = *(const bf16x8*)qsrc;
    bf16x8 t1 = *(const bf16x8*)(qsrc + 32);
#pragma unroll
    for (int e = 0; e < 8; ++e) {
      aq0[e] = (__bf16)((float)t0[e] * 0.125f);
      aq1[e] = (__bf16)((float)t1[e] * 0.125f);
    }
  }

  float mreg[4], lreg[4];
#pragma unroll
  for (int rr = 0; rr < 4; ++rr) { mreg[rr] = -1e30f; lreg[rr] = 0.f; }
  f32x4 acc_o[4] = {};

  int clist[8]; int ncl = 0;
  clist[ncl++] = 0;
  if (qmax >= 64) clist[ncl++] = 64;
  {
    int lo = 1984 - qmax; if (lo < 0) lo = 0; lo &= ~63;
    const int hik = min(qmax, 2048 - q0);
    for (int c = lo; c <= hik; c += 64)
      if (c >= 128) clist[ncl++] = c;
  }

  // prologue: tile-0 K/V into registers (T14 pipeline)
  bf16x8 k0r, var;
  {
    const __bf16* src = qu + (bL + clist[0] + krow_st) * QS + 512 + h * 64;
    k0r = *(const bf16x8*)(src + kgb8 * 8);
    const __bf16* vsrc = qu + (bL + clist[0] + lane) * QS + 1024 + h * 64 + w * 8;
    var = *(const bf16x8*)vsrc;
  }

  for (int ci = 0; ci < ncl; ++ci) {
    const int c0 = clist[ci];
    // block-uniform tile classification
    const bool thin = (c0 == 64) && (qmax <= 1856);   // only col j=64 valid
    const bool fast0 = (c0 == 0) && (q0 >= 64) && (qmax + 63 <= 2048);

    WAIT_VM(0);                                 // this tile's K/V landed
    SB0; __builtin_amdgcn_s_barrier(); SB0;     // WAR: prior tile's reads done
    {
      char* lkb = (char*)lK;
      const int sw = (krow_st & 7) << 4;
      *(bf16x8*)(lkb + ((krow_st * 128 + kgb8 * 16) ^ sw)) = k0r;
#pragma unroll
      for (int e = 0; e < 8; ++e)
        lV[(w * 8 + e) * SP + lane] = var[e];
    }
    if (ci + 1 < ncl) {                         // issue next tile's loads
      const int cn = clist[ci + 1];
      const __bf16* src = qu + (bL + cn + krow_st) * QS + 512 + h * 64;
      k0r = *(const bf16x8*)(src + kgb8 * 8);
      const __bf16* vsrc = qu + (bL + cn + lane) * QS + 1024 + h * 64 + w * 8;
      var = *(const bf16x8*)vsrc;
    }
    WAIT_LGKM0;                                 // my ds_writes retired
    SB0; __builtin_amdgcn_s_barrier(); SB0;     // RAW: all writes visible

    // QK^T (nt=0 only on thin tiles)
    f32x4 s[4];
    {
      const char* lkb = (const char*)lK;
      auto qk = [&](int nt) {
        const int krow = nt * 16 + cc;
        const int sw = (krow & 7) << 4;
        bf16x8 bk0 = *(const bf16x8*)(lkb + ((krow * 128 + cq * 16) ^ sw));
        bf16x8 bk1 = *(const bf16x8*)(lkb + ((krow * 128 + 64 + cq * 16) ^ sw));
        f32x4 a = {};
        a = __builtin_amdgcn_mfma_f32_16x16x32_bf16(aq0, bk0, a, 0, 0, 0);
        a = __builtin_amdgcn_mfma_f32_16x16x32_bf16(aq1, bk1, a, 0, 0, 0);
        s[nt] = a;
      };
      qk(0);
      if (!thin) { qk(1); qk(2); qk(3); }
    }

    // mask (Q pre-scaled; no *0.125 here)
    if (!fast0) {
      const int ntm = thin ? 1 : 4;
      if (c0 >= 128) {
        // band-only mask: glob (j<=64) impossible here
        for (int nt = 0; nt < 4; ++nt) {
          if (nt >= ntm) break;
#pragma unroll
          for (int rr = 0; rr < 4; ++rr) {
            const int i = q0 + w * 16 + cq * 4 + rr;
            const int j = c0 + nt * 16 + cc;
            const int ij = i + j;
            const bool valid = (j <= i) && (ij >= 1984) && (ij <= 2048);
            s[nt][rr] = valid ? s[nt][rr] : -1e30f;
          }
        }
      } else {
        for (int nt = 0; nt < 4; ++nt) {
          if (nt >= ntm) break;
#pragma unroll
          for (int rr = 0; rr < 4; ++rr) {
            const int i = q0 + w * 16 + cq * 4 + rr;
            const int j = c0 + nt * 16 + cc;
            const int ij = i + j;
            const bool valid = (j <= i) &&
                ((ij >= 1984 && ij <= 2048) || (j <= 64 && ij <= 2048));
            s[nt][rr] = valid ? s[nt][rr] : -1e30f;
          }
        }
      }
    }

    // row max (in-lane over active nt, then 16-lane shfl tree)
    f32x4 pm;
#pragma unroll
    for (int rr = 0; rr < 4; ++rr) pm[rr] = s[0][rr];
    if (!thin) {
#pragma unroll
      for (int rr = 0; rr < 4; ++rr)
        pm[rr] = fmaxf(fmaxf(pm[rr], s[1][rr]), fmaxf(s[2][rr], s[3][rr]));
    }
#pragma unroll
    for (int m = 1; m < 16; m <<= 1) {
#pragma unroll
      for (int rr = 0; rr < 4; ++rr)
        pm[rr] = fmaxf(pm[rr], __shfl_xor(pm[rr], m, 64));
    }
    float corr[4];
#pragma unroll
    for (int rr = 0; rr < 4; ++rr) {
      const float nm = fmaxf(mreg[rr], pm[rr]);
      corr[rr] = __expf(mreg[rr] - nm);
      mreg[rr] = nm;
    }

    // P = exp(s - m); thin: write nt=0, zero slots 16..31 (PV k<=31 reads)
    f32x4 ps = {};
    if (thin) {
#pragma unroll
      for (int rr = 0; rr < 4; ++rr) {
        const float p = __expf(s[0][rr] - mreg[rr]);
        ps[rr] += p;
        const int prow = (w * 16 + cq * 4 + rr) * SP;
        Pb[prow + cc] = (__bf16)p;
        Pb[prow + 16 + cc] = (__bf16)0.f;
      }
    } else {
#pragma unroll
      for (int nt = 0; nt < 4; ++nt) {
#pragma unroll
        for (int rr = 0; rr < 4; ++rr) {
          const float p = __expf(s[nt][rr] - mreg[rr]);
          ps[rr] += p;
          Pb[(w * 16 + cq * 4 + rr) * SP + nt * 16 + cc] = (__bf16)p;
        }
      }
    }
#pragma unroll
    for (int m = 1; m < 16; m <<= 1) {
#pragma unroll
      for (int rr = 0; rr < 4; ++rr)
        ps[rr] += __shfl_xor(ps[rr], m, 64);
    }
#pragma unroll
    for (int rr = 0; rr < 4; ++rr) lreg[rr] = lreg[rr] * corr[rr] + ps[rr];

    // PV (thin: k=0..31 half only -> 4 MFMA)
    {
      bf16x8 pa0 = *(const bf16x8*)(Pb + (w * 16 + cc) * SP + cq * 8);
      if (thin) {
#pragma unroll
        for (int dt = 0; dt < 4; ++dt) {
#pragma unroll
          for (int rr = 0; rr < 4; ++rr) acc_o[dt][rr] *= corr[rr];
          bf16x8 vb0 = *(const bf16x8*)(lV + (dt * 16 + cc) * SP + cq * 8);
          acc_o[dt] = __builtin_amdgcn_mfma_f32_16x16x32_bf16(pa0, vb0, acc_o[dt], 0, 0, 0);
        }
      } else {
        bf16x8 pa1 = *(const bf16x8*)(Pb + (w * 16 + cc) * SP + 32 + cq * 8);
#pragma unroll
        for (int dt = 0; dt < 4; ++dt) {
#pragma unroll
          for (int rr = 0; rr < 4; ++rr) acc_o[dt][rr] *= corr[rr];
          bf16x8 vb0 = *(const bf16x8*)(lV + (dt * 16 + cc) * SP + cq * 8);
          bf16x8 vb1 = *(const bf16x8*)(lV + (dt * 16 + cc) * SP + 32 + cq * 8);
          acc_o[dt] = __builtin_amdgcn_mfma_f32_16x16x32_bf16(pa0, vb0, acc_o[dt], 0, 0, 0);
          acc_o[dt] = __builtin_amdgcn_mfma_f32_16x16x32_bf16(pa1, vb1, acc_o[dt], 0, 0, 0);
        }
      }
    }
  }

  // epilogue: register state only
#pragma unroll
  for (int dt = 0; dt < 4; ++dt) {
#pragma unroll
    for (int rr = 0; rr < 4; ++rr) {
      const int row16 = cq * 4 + rr;
      const size_t qrow = bL + q0 + w * 16 + row16;
      const int d = dt * 16 + cc;
      const float o = acc_o[dt][rr] / fmaxf(lreg[rr], 1e-30f);
      const float uv = (float)qu[qrow * QS + 1536 + h * 64 + d];
      g[qrow * D_ + h * 64 + d] = (__bf16)(o / (1.f + __expf(-o)) * uv);
    }
  }
}

extern "C" void kernel_launch(void* const* d_in, const int* in_sizes, int n_in,
                              void* d_out, int out_size, void* d_ws, size_t ws_size,
                              hipStream_t stream) {
  const float* x     = (const float*)d_in[0];
  const float* w_qkv = (const float*)d_in[1];
  const float* b_qkv = (const float*)d_in[2];
  const float* w_u   = (const float*)d_in[3];
  const float* b_u   = (const float*)d_in[4];
  const float* w_out = (const float*)d_in[5];
  const float* b_out = (const float*)d_in[6];
  float* out = (float*)d_out;

  char* ws = (char*)d_ws;
  __bf16* xb   = (__bf16*)ws;                           //  8 MB
  __bf16* wcat = (__bf16*)(ws + 8388608);               //  2 MB [w_qkv;w_u]
  __bf16* wob  = (__bf16*)(ws + 10485760);              //  0.5 MB
  float*  bcat = (float*) (ws + 11010048);              //  8 KB
  __bf16* qu   = (__bf16*)(ws + 11018240);              // 32 MB [q|k|v|u]
  __bf16* gb   = (__bf16*)(ws + 44572672);              //  8 MB

  // one-time opt-in for 64 KB dynamic LDS (host-side attr, graph-safe)
  static bool attr_done = []() {
    hipFuncSetAttribute((const void*)gemm128,
                        hipFuncAttributeMaxDynamicSharedMemorySize, 65536);
    return true;
  }();
  (void)attr_done;

  cvt_pack<<<dim3(2688), dim3(256), 0, stream>>>(
      x, w_qkv, w_u, w_out, b_qkv, b_u, xb, wcat, wob, bcat);
  gemm128<<<dim3(64, 16), dim3(256), 65536, stream>>>(
      xb, wcat, bcat, qu, 8192, 2048, 512);
  attn_tile<<<dim3(L_ / 128, H_, B_), dim3(512), 0, stream>>>(qu, gb);
  gemm_out<<<dim3(128, 4), dim3(256), 0, stream>>>(
      gb, wob, b_out, out);
}